// Round 7
// baseline (1090.593 us; speedup 1.0000x reference)
//
#include <hip/hip_runtime.h>
#include <stdint.h>
#include <stddef.h>

#define VOCAB 32000
#define HID   1024
#define NB    32
#define SLEN  64
#define TLEN  64
#define G3    3072

typedef float          f32x4  __attribute__((ext_vector_type(4)));
typedef float          f32x2  __attribute__((ext_vector_type(2)));
typedef __bf16         bf16x8 __attribute__((ext_vector_type(8)));
typedef unsigned short u16x8  __attribute__((ext_vector_type(8)));
typedef unsigned short u16x4  __attribute__((ext_vector_type(4)));
typedef unsigned int   u32x4  __attribute__((ext_vector_type(4)));

union BfPun { u16x8 u; bf16x8 b; };
union CvPun { u32x4 u; bf16x8 b; };

__device__ __forceinline__ unsigned short f2bf(float f) {
  unsigned int u = __builtin_bit_cast(unsigned int, f);
  u += 0x7FFFu + ((u >> 16) & 1u);   // RNE round to bf16
  return (unsigned short)(u >> 16);
}

// async global -> LDS, 16 B per lane (LDS dest must be wave-uniform base + lane*16)
__device__ __forceinline__ void gld_lds16(const unsigned short* g, unsigned short* l) {
  __builtin_amdgcn_global_load_lds(
      (const __attribute__((address_space(1))) unsigned int*)g,
      (__attribute__((address_space(3))) unsigned int*)l,
      16, 0, 0);
}

// ---------------- converts / gathers / init ----------------

__global__ __launch_bounds__(256) void cvt_bf16(const float* __restrict__ in,
                                                unsigned short* __restrict__ out) {
  size_t idx = ((size_t)blockIdx.x * 256 + threadIdx.x) * 4;
  f32x4 v = *(const f32x4*)(in + idx);
  u16x4 o;
  o[0] = f2bf(v[0]); o[1] = f2bf(v[1]); o[2] = f2bf(v[2]); o[3] = f2bf(v[3]);
  *(u16x4*)(out + idx) = o;
}

// W_ih_d [3072][2048] -> W1 (cols 0..1023), W2 (cols 1024..2047), both bf16 [3072][1024]
__global__ __launch_bounds__(256) void cvt_split_d(const float* __restrict__ Wd,
                                                   unsigned short* __restrict__ W1,
                                                   unsigned short* __restrict__ W2) {
  int r = blockIdx.x, q = threadIdx.x;
  const float* src = Wd + (size_t)r * 2048;
  f32x4 v1 = *(const f32x4*)(src + q * 4);
  f32x4 v2 = *(const f32x4*)(src + 1024 + q * 4);
  u16x4 o1, o2;
  o1[0]=f2bf(v1[0]); o1[1]=f2bf(v1[1]); o1[2]=f2bf(v1[2]); o1[3]=f2bf(v1[3]);
  o2[0]=f2bf(v2[0]); o2[1]=f2bf(v2[1]); o2[2]=f2bf(v2[2]); o2[3]=f2bf(v2[3]);
  *(u16x4*)(W1 + (size_t)r * 1024 + q * 4) = o1;
  *(u16x4*)(W2 + (size_t)r * 1024 + q * 4) = o2;
}

// W_hh [3H][H] fp32 -> fragment-linear bf16: Wv[blk][g][ks][lane][8]
__global__ __launch_bounds__(128) void cvt_whh_frag(const float* __restrict__ W,
                                                    unsigned short* __restrict__ Wv) {
  int r = blockIdx.x;              // 0..3071
  int g = r >> 10, i = r & 1023, blk = i >> 4, il = i & 15;
  int q = threadIdx.x;             // 8-elem chunk 0..127
  int ks = q >> 2, ksub = q & 3, lane = il + ksub * 16;
  f32x4 v0 = *(const f32x4*)(W + (size_t)r * HID + q * 8);
  f32x4 v1 = *(const f32x4*)(W + (size_t)r * HID + q * 8 + 4);
  u16x8 o;
  o[0]=f2bf(v0[0]); o[1]=f2bf(v0[1]); o[2]=f2bf(v0[2]); o[3]=f2bf(v0[3]);
  o[4]=f2bf(v1[0]); o[5]=f2bf(v1[1]); o[6]=f2bf(v1[2]); o[7]=f2bf(v1[3]);
  size_t dst = ((((size_t)blk * 3 + g) * 32 + ks) * 64 + lane) * 8;
  *(u16x8*)(Wv + dst) = o;
}

__global__ __launch_bounds__(256) void gather_embed(const int* __restrict__ seqs,
                                                    const float* __restrict__ emb,
                                                    unsigned short* __restrict__ Aout,
                                                    int relu) {
  int r = blockIdx.x, q = threadIdx.x;
  int tok = seqs[r];
  f32x4 v = *(const f32x4*)(emb + (size_t)tok * HID + q * 4);
  if (relu) {
    v[0]=fmaxf(v[0],0.f); v[1]=fmaxf(v[1],0.f); v[2]=fmaxf(v[2],0.f); v[3]=fmaxf(v[3],0.f);
  }
  u16x4 o; o[0]=f2bf(v[0]); o[1]=f2bf(v[1]); o[2]=f2bf(v[2]); o[3]=f2bf(v[3]);
  *(u16x4*)(Aout + (size_t)r * HID + q * 4) = o;
}

// relu(thought) -> bf16, rows 32..127 zero-padded
__global__ __launch_bounds__(256) void gather_thought(const float* __restrict__ hfin,
                                                      unsigned short* __restrict__ Aout) {
  int r = blockIdx.x, q = threadIdx.x;
  u16x4 o = {0, 0, 0, 0};
  if (r < NB) {
    f32x4 v = *(const f32x4*)(hfin + (size_t)r * HID + q * 4);
    o[0]=f2bf(fmaxf(v[0],0.f)); o[1]=f2bf(fmaxf(v[1],0.f));
    o[2]=f2bf(fmaxf(v[2],0.f)); o[3]=f2bf(fmaxf(v[3],0.f));
  }
  *(u16x4*)(Aout + (size_t)r * HID + q * 4) = o;
}

__global__ __launch_bounds__(256) void zero_f32(float* __restrict__ p) {
  p[blockIdx.x * 256 + threadIdx.x] = 0.f;
}

// ---------------- bf16 MFMA GEMM: C = A[M,1024] * B[N,1024]^T (+ epilogue) ----------------
// 128x128 tile, BK=32, global_load_lds width-16 staging (m97 structure).
// 1-D grid; XCD-chunked swizzle + (MT x 4) supertile.
template<int MODE, int MT>
__global__ __launch_bounds__(256) void gemm_bf16(const unsigned short* __restrict__ A,
                                                 const unsigned short* __restrict__ Bw,
                                                 const float* __restrict__ bias,
                                                 const float* __restrict__ add2,
                                                 float* __restrict__ out, int N) {
  __shared__ unsigned short Abuf[128 * 32];
  __shared__ unsigned short Bbuf[128 * 32];
  const int K = HID;
  int tid = threadIdx.x, lane = tid & 63, wid = tid >> 6;
  int nwg = gridDim.x;
  int u = (blockIdx.x & 7) * (nwg >> 3) + (blockIdx.x >> 3);
  int g = u / (MT * 4);
  int r_ = u - g * (MT * 4);
  int bm = r_ % MT;
  int bn = g * 4 + r_ / MT;
  int wrow = wid >> 1, wcol = wid & 1;
  f32x4 zero4 = {0.f, 0.f, 0.f, 0.f};
  f32x4 acc[4][4];
#pragma unroll
  for (int i = 0; i < 4; ++i)
#pragma unroll
    for (int j = 0; j < 4; ++j) acc[i][j] = zero4;

  int srow = tid >> 2, spart = tid & 3;
  const unsigned short* Ag = A + ((size_t)bm * 128 + srow) * K + spart * 8;
  const unsigned short* Bg = Bw + ((size_t)bn * 128 + srow) * K + spart * 8;
  unsigned short* As = Abuf + tid * 8;       // linear: lane*16B within wave
  unsigned short* Bs = Bbuf + tid * 8;

  for (int ks = 0; ks < 32; ++ks) {
    int k0 = ks * 32;
    __syncthreads();                          // prev MFMA ds_reads done
    gld_lds16(Ag + k0, As);
    gld_lds16(Ag + (size_t)64 * K + k0, As + 64 * 32);
    gld_lds16(Bg + k0, Bs);
    gld_lds16(Bg + (size_t)64 * K + k0, Bs + 64 * 32);
    __syncthreads();                          // vmcnt(0) drain -> LDS valid
    bf16x8 af[4], bfr[4];
#pragma unroll
    for (int mi = 0; mi < 4; ++mi) {
      BfPun tpun;
      tpun.u = *(const u16x8*)(Abuf + (wrow * 64 + mi * 16 + (lane & 15)) * 32 + (lane >> 4) * 8);
      af[mi] = tpun.b;
    }
#pragma unroll
    for (int ni = 0; ni < 4; ++ni) {
      BfPun tpun;
      tpun.u = *(const u16x8*)(Bbuf + (wcol * 64 + ni * 16 + (lane & 15)) * 32 + (lane >> 4) * 8);
      bfr[ni] = tpun.b;
    }
#pragma unroll
    for (int mi = 0; mi < 4; ++mi)
#pragma unroll
      for (int ni = 0; ni < 4; ++ni)
        acc[mi][ni] = __builtin_amdgcn_mfma_f32_16x16x32_bf16(af[mi], bfr[ni], acc[mi][ni], 0, 0, 0);
  }

#pragma unroll
  for (int mi = 0; mi < 4; ++mi) {
    int rb = bm * 128 + wrow * 64 + mi * 16 + ((lane >> 4) << 2);
#pragma unroll
    for (int ni = 0; ni < 4; ++ni) {
      int c = bn * 128 + wcol * 64 + ni * 16 + (lane & 15);
#pragma unroll
      for (int e = 0; e < 4; ++e) {
        int r = rb + e;
        float v = acc[mi][ni][e];
        if (MODE == 0) {
          out[(size_t)r * N + c] = v + bias[c];
        } else if (MODE == 1) {
          int t = r & 63, b = r >> 6;
          int gg = c >> 10, ci = c & 1023;
          out[(((size_t)t * 3 + gg) * NB + b) * HID + ci] = v + bias[c];
        } else if (MODE == 2) {
          int t = r & 63, b = r >> 6;
          int gg = c >> 10, ci = c & 1023;
          out[(((size_t)t * 3 + gg) * NB + b) * HID + ci] = v + add2[(size_t)b * G3 + c];
        } else {
          int b = r & 31, t = r >> 5;
          out[((size_t)b * TLEN + t) * VOCAB + c] = v + bias[c];
        }
      }
    }
  }
}

// ---------------- persistent GRU scan (MFMA, fragment-linear layouts) ----------------
// 64 blocks x 384 threads (6 waves = 3 gates x 2 batch-halves).
// Cross-block sync: write-once flags[t][blk] (parallel agent stores, no RMW
// contention) + per-lane atomic-load poll (one L3 round trip per iteration).
__global__ __launch_bounds__(384, 1) void gru_scan(
    const unsigned short* __restrict__ Wv,   // [64][3][32][64][8] bf16
    const float* __restrict__ b_hh,
    const float* __restrict__ xpT,           // [T][3][NB][HID]
    unsigned short* __restrict__ hbx,        // [nsteps][2][32][64][8] write-once
    const int* __restrict__ lens,            // null => no freeze (decoder)
    unsigned short* __restrict__ hs_out,     // null for encoder; [T*NB][HID] bf16
    float* __restrict__ hfin,                // final h fp32 (encoder) or null
    int* __restrict__ flags, int nsteps) {   // flags[t*64+blk], zeroed per launch
  __shared__ unsigned short Wlds[49152];     // 96 KB
  __shared__ float gh[48][33];
  __shared__ float h32[32][16];
  __shared__ float bhh_s[48];
  __shared__ int   lens_s[32];
  int tid = threadIdx.x, lane = tid & 63, w = tid >> 6;
  int g = w >> 1, part = w & 1;
  int blk = blockIdx.x, i0 = blk * 16;

  if (tid < 32) lens_s[tid] = lens ? lens[tid] : 0x7fffffff;
  if (tid >= 64 && tid < 112) {
    int q = tid - 64;
    bhh_s[q] = b_hh[(size_t)(q >> 4) * HID + i0 + (q & 15)];
  }
  if (tid < 256) h32[tid >> 3][((tid & 7) * 2)] = 0.f;
  if (tid < 256) h32[tid >> 3][((tid & 7) * 2) + 1] = 0.f;

  // stage W fragment slice into LDS (one time)
  {
    const unsigned short* Wsrc = Wv + (size_t)blk * 49152;
    for (int j = tid; j < 6144; j += 384)
      *(u16x8*)(Wlds + (size_t)j * 8) = *(const u16x8*)(Wsrc + (size_t)j * 8);
  }
  __syncthreads();

  int eb = tid >> 3, eil = (tid & 7) * 2;
  f32x2 xr2, xz2, xn2;

  for (int t = 0; t < nsteps; ++t) {
    // xp loads for step t: issued first, complete under the MFMA phase
    if (tid < 256) {
      const float* xb = xpT + ((size_t)t * 3 * NB + eb) * HID + i0 + eil;
      xr2 = *(const f32x2*)(xb);
      xz2 = *(const f32x2*)(xb + (size_t)NB * HID);
      xn2 = *(const f32x2*)(xb + (size_t)2 * NB * HID);
    }
    f32x4 acc = {0.f, 0.f, 0.f, 0.f};
    if (t > 0) {
      const unsigned short* hp = hbx + (size_t)(t - 1) * 32768 + part * 16384 + lane * 8;
      u32x4 pb[16];
#pragma unroll
      for (int j = 0; j < 16; ++j) pb[j] = *(const u32x4*)(hp + (size_t)j * 512);
#pragma unroll
      for (int ks = 0; ks < 32; ++ks) {
        BfPun a_;
        a_.u = *(const u16x8*)(Wlds + ((size_t)(g * 32 + ks) * 64 + lane) * 8);
        CvPun cv; cv.u = pb[ks & 15];
        if (ks + 16 < 32) pb[ks & 15] = *(const u32x4*)(hp + (size_t)(ks + 16) * 512);
        acc = __builtin_amdgcn_mfma_f32_16x16x32_bf16(a_.b, cv.b, acc, 0, 0, 0);
      }
    }
    {
      int il4 = (lane >> 4) * 4, cb = part * 16 + (lane & 15);
#pragma unroll
      for (int e = 0; e < 4; ++e) gh[g * 16 + il4 + e][cb] = acc[e];
    }
    __syncthreads();

    if (tid < 256) {
      float sr0 = gh[eil][eb],      sr1 = gh[eil + 1][eb];
      float sz0 = gh[16 + eil][eb], sz1 = gh[16 + eil + 1][eb];
      float sn0 = gh[32 + eil][eb], sn1 = gh[32 + eil + 1][eb];
      float rg0 = 1.f / (1.f + __expf(-(xr2[0] + sr0 + bhh_s[eil])));
      float rg1 = 1.f / (1.f + __expf(-(xr2[1] + sr1 + bhh_s[eil + 1])));
      float zg0 = 1.f / (1.f + __expf(-(xz2[0] + sz0 + bhh_s[16 + eil])));
      float zg1 = 1.f / (1.f + __expf(-(xz2[1] + sz1 + bhh_s[16 + eil + 1])));
      float ng0 = tanhf(xn2[0] + rg0 * (sn0 + bhh_s[32 + eil]));
      float ng1 = tanhf(xn2[1] + rg1 * (sn1 + bhh_s[32 + eil + 1]));
      float h0o = h32[eb][eil], h1o = h32[eb][eil + 1];
      float hn0 = (1.f - zg0) * ng0 + zg0 * h0o;
      float hn1 = (1.f - zg1) * ng1 + zg1 * h1o;
      if (t >= lens_s[eb]) { hn0 = h0o; hn1 = h1o; }   // packed-seq freeze
      h32[eb][eil] = hn0; h32[eb][eil + 1] = hn1;
      unsigned int pk = (unsigned int)f2bf(hn0) | ((unsigned int)f2bf(hn1) << 16);
      int k = i0 + eil;
      int ksf = k >> 5, lnf = (eb & 15) + ((k >> 3) & 3) * 16, sub = k & 7;
      unsigned short* dst = hbx + (size_t)t * 32768 + (size_t)(eb >> 4) * 16384
                            + (size_t)ksf * 512 + lnf * 8 + sub;
      __hip_atomic_store((unsigned int*)dst, pk, __ATOMIC_RELAXED, __HIP_MEMORY_SCOPE_AGENT);
      if (hs_out)
        *(unsigned int*)(hs_out + ((size_t)t * NB + eb) * HID + k) = pk;
    }

    if (t + 1 < nsteps) {
      __syncthreads();   // vmcnt(0) drain: this block's hbx stores visible at L3
      if (tid == 0)
        __hip_atomic_store(&flags[t * 64 + blk], 1, __ATOMIC_RELAXED, __HIP_MEMORY_SCOPE_AGENT);
      if (tid < 64) {
        while (__hip_atomic_load(&flags[t * 64 + tid], __ATOMIC_RELAXED, __HIP_MEMORY_SCOPE_AGENT) == 0)
          __builtin_amdgcn_s_sleep(1);
      }
      __syncthreads();   // all h(t) visible; step t+1 loads ordered after poll
    }
  }

  if (hfin && tid < 256) {
    f32x2 hv; hv[0] = h32[eb][eil]; hv[1] = h32[eb][eil + 1];
    *(f32x2*)(hfin + (size_t)eb * HID + i0 + eil) = hv;
  }
}

// ---------------- LDS-staged in-place row log_softmax on d_out [2048 x 32000] ----------------
__global__ __launch_bounds__(1024, 1) void log_softmax_lds(float* __restrict__ out) {
  __shared__ float rowbuf[VOCAB];            // 128000 B
  __shared__ float ms[16], ss[16];
  size_t row = blockIdx.x;
  float* p = out + row * VOCAB;
  const f32x4* p4 = (const f32x4*)p;
  int tid = threadIdx.x;
  float m = -3.0e38f, s = 0.f;
  for (int j = tid; j < VOCAB / 4; j += 1024) {
    f32x4 v = p4[j];
    *(f32x4*)(rowbuf + j * 4) = v;
#pragma unroll
    for (int e = 0; e < 4; ++e) {
      float x = v[e];
      float nm = fmaxf(m, x);
      s = s * __expf(m - nm) + __expf(x - nm);
      m = nm;
    }
  }
#pragma unroll
  for (int off = 1; off < 64; off <<= 1) {
    float m2 = __shfl_xor(m, off, 64);
    float s2 = __shfl_xor(s, off, 64);
    float nm = fmaxf(m, m2);
    s = s * __expf(m - nm) + s2 * __expf(m2 - nm);
    m = nm;
  }
  if ((tid & 63) == 0) { ms[tid >> 6] = m; ss[tid >> 6] = s; }
  __syncthreads();
  float M = -3.0e38f;
#pragma unroll
  for (int i = 0; i < 16; ++i) M = fmaxf(M, ms[i]);
  float S = 0.f;
#pragma unroll
  for (int i = 0; i < 16; ++i) S += ss[i] * __expf(ms[i] - M);
  float lse = M + __logf(S);
  f32x4* o4 = (f32x4*)p;
  for (int j = tid; j < VOCAB / 4; j += 1024) {
    f32x4 v = *(const f32x4*)(rowbuf + j * 4);
    v[0] -= lse; v[1] -= lse; v[2] -= lse; v[3] -= lse;
    o4[j] = v;
  }
}

// ---------------- host ----------------

extern "C" void kernel_launch(void* const* d_in, const int* in_sizes, int n_in,
                              void* d_out, int out_size, void* d_ws, size_t ws_size,
                              hipStream_t stream) {
  (void)in_sizes; (void)n_in; (void)out_size; (void)ws_size;
  const int*   input_seqs  = (const int*)d_in[0];
  const int*   target_seqs = (const int*)d_in[1];
  const int*   input_lens  = (const int*)d_in[2];
  const float* emb_enc = (const float*)d_in[3];
  const float* W_ih_e  = (const float*)d_in[4];
  const float* W_hh_e  = (const float*)d_in[5];
  const float* b_ih_e  = (const float*)d_in[6];
  const float* b_hh_e  = (const float*)d_in[7];
  const float* emb_dec = (const float*)d_in[8];
  const float* W_ih_d  = (const float*)d_in[9];
  const float* W_hh_d  = (const float*)d_in[10];
  const float* b_ih_d  = (const float*)d_in[11];
  const float* b_hh_d  = (const float*)d_in[12];
  const float* W_out   = (const float*)d_in[13];
  const float* b_out   = (const float*)d_in[14];
  float* out = (float*)d_out;

  char* p = (char*)d_ws;
  auto take = [&](size_t n) { char* q = p; p += (n + 255) & ~(size_t)255; return q; };
  unsigned short* Wbf_e  = (unsigned short*)take((size_t)G3 * HID * 2);
  unsigned short* Wbf_1d = (unsigned short*)take((size_t)G3 * HID * 2);
  unsigned short* Wbf_2d = (unsigned short*)take((size_t)G3 * HID * 2);
  unsigned short* Wbf_o  = (unsigned short*)take((size_t)VOCAB * HID * 2);
  unsigned short* Wv_e   = (unsigned short*)take((size_t)G3 * HID * 2);
  unsigned short* Wv_d   = (unsigned short*)take((size_t)G3 * HID * 2);
  unsigned short* A_ed   = (unsigned short*)take((size_t)2048 * HID * 2);
  unsigned short* A_th   = (unsigned short*)take((size_t)128 * HID * 2);
  unsigned short* A_hs   = (unsigned short*)take((size_t)2048 * HID * 2);
  float* xpT = (float*)take((size_t)64 * 3 * NB * HID * 4);
  float* t2  = (float*)take((size_t)128 * G3 * 4);
  unsigned short* hbx_e = (unsigned short*)take((size_t)SLEN * NB * HID * 2);
  unsigned short* hbx_d = (unsigned short*)take((size_t)TLEN * NB * HID * 2);
  int*   flags_e = (int*)take((size_t)SLEN * 64 * 4);   // write-once barrier flags
  int*   flags_d = (int*)take((size_t)TLEN * 64 * 4);
  float* hfin = (float*)take((size_t)NB * HID * 4);

  // weight converts (fp32 -> bf16)
  cvt_bf16<<<dim3((G3 * HID) / 1024), 256, 0, stream>>>(W_ih_e, Wbf_e);
  cvt_split_d<<<dim3(G3), 256, 0, stream>>>(W_ih_d, Wbf_1d, Wbf_2d);
  cvt_bf16<<<dim3((VOCAB * HID) / 1024), 256, 0, stream>>>(W_out, Wbf_o);
  cvt_whh_frag<<<dim3(G3), 128, 0, stream>>>(W_hh_e, Wv_e);
  cvt_whh_frag<<<dim3(G3), 128, 0, stream>>>(W_hh_d, Wv_d);
  zero_f32<<<dim3(32), 256, 0, stream>>>((float*)flags_e);   // flags_e + flags_d (32 KB)

  // ---- encoder ----
  gather_embed<<<dim3(NB * SLEN), 256, 0, stream>>>(input_seqs, emb_enc, A_ed, 0);
  gemm_bf16<1, 16><<<dim3(384), 256, 0, stream>>>(A_ed, Wbf_e, b_ih_e, nullptr, xpT, G3);
  gru_scan<<<dim3(64), 384, 0, stream>>>(Wv_e, b_hh_e, xpT, hbx_e, input_lens,
                                         nullptr, hfin, flags_e, SLEN);

  // ---- decoder pre ----
  gather_thought<<<dim3(128), 256, 0, stream>>>(hfin, A_th);
  gemm_bf16<0, 1><<<dim3(24), 256, 0, stream>>>(A_th, Wbf_2d, b_ih_d, nullptr, t2, G3);
  gather_embed<<<dim3(NB * TLEN), 256, 0, stream>>>(target_seqs, emb_dec, A_ed, 1);
  gemm_bf16<2, 16><<<dim3(384), 256, 0, stream>>>(A_ed, Wbf_1d, nullptr, t2, xpT, G3);

  // ---- decoder scan ----
  gru_scan<<<dim3(64), 384, 0, stream>>>(Wv_d, b_hh_d, xpT, hbx_d, nullptr,
                                         A_hs, nullptr, flags_d, TLEN);

  // ---- logits (direct to d_out) + in-place log_softmax ----
  gemm_bf16<3, 16><<<dim3(4000), 256, 0, stream>>>(A_hs, Wbf_o, b_out, nullptr, out, VOCAB);
  log_softmax_lds<<<dim3(NB * TLEN), 1024, 0, stream>>>(out);
}

// Round 8
// 892.366 us; speedup vs baseline: 1.2221x; 1.2221x over previous
//
#include <hip/hip_runtime.h>
#include <stdint.h>
#include <stddef.h>

#define VOCAB 32000
#define HID   1024
#define NB    32
#define SLEN  64
#define TLEN  64
#define G3    3072

typedef float          f32x4  __attribute__((ext_vector_type(4)));
typedef float          f32x2  __attribute__((ext_vector_type(2)));
typedef __bf16         bf16x8 __attribute__((ext_vector_type(8)));
typedef unsigned short u16x8  __attribute__((ext_vector_type(8)));
typedef unsigned short u16x4  __attribute__((ext_vector_type(4)));
typedef unsigned int   u32x4  __attribute__((ext_vector_type(4)));

union BfPun { u16x8 u; bf16x8 b; };
union CvPun { u32x4 u; bf16x8 b; };

__device__ __forceinline__ unsigned short f2bf(float f) {
  unsigned int u = __builtin_bit_cast(unsigned int, f);
  u += 0x7FFFu + ((u >> 16) & 1u);   // RNE round to bf16
  return (unsigned short)(u >> 16);
}

// fast sigmoid / tanh via v_exp + v_rcp (approx rcp, ~1 ulp — fine vs 0.24 abs tol)
__device__ __forceinline__ float sig_f(float x) {
  return __builtin_amdgcn_rcpf(1.f + __expf(-x));
}
__device__ __forceinline__ float tanh_f(float x) {
  return 2.f * __builtin_amdgcn_rcpf(1.f + __expf(-2.f * x)) - 1.f;
}

// async global -> LDS, 16 B per lane (LDS dest must be wave-uniform base + lane*16)
__device__ __forceinline__ void gld_lds16(const unsigned short* g, unsigned short* l) {
  __builtin_amdgcn_global_load_lds(
      (const __attribute__((address_space(1))) unsigned int*)g,
      (__attribute__((address_space(3))) unsigned int*)l,
      16, 0, 0);
}

// ---------------- converts / gathers / init ----------------

__global__ __launch_bounds__(256) void cvt_bf16(const float* __restrict__ in,
                                                unsigned short* __restrict__ out) {
  size_t idx = ((size_t)blockIdx.x * 256 + threadIdx.x) * 4;
  f32x4 v = *(const f32x4*)(in + idx);
  u16x4 o;
  o[0] = f2bf(v[0]); o[1] = f2bf(v[1]); o[2] = f2bf(v[2]); o[3] = f2bf(v[3]);
  *(u16x4*)(out + idx) = o;
}

// W_ih_d [3072][2048] -> W1 (cols 0..1023), W2 (cols 1024..2047), both bf16 [3072][1024]
__global__ __launch_bounds__(256) void cvt_split_d(const float* __restrict__ Wd,
                                                   unsigned short* __restrict__ W1,
                                                   unsigned short* __restrict__ W2) {
  int r = blockIdx.x, q = threadIdx.x;
  const float* src = Wd + (size_t)r * 2048;
  f32x4 v1 = *(const f32x4*)(src + q * 4);
  f32x4 v2 = *(const f32x4*)(src + 1024 + q * 4);
  u16x4 o1, o2;
  o1[0]=f2bf(v1[0]); o1[1]=f2bf(v1[1]); o1[2]=f2bf(v1[2]); o1[3]=f2bf(v1[3]);
  o2[0]=f2bf(v2[0]); o2[1]=f2bf(v2[1]); o2[2]=f2bf(v2[2]); o2[3]=f2bf(v2[3]);
  *(u16x4*)(W1 + (size_t)r * 1024 + q * 4) = o1;
  *(u16x4*)(W2 + (size_t)r * 1024 + q * 4) = o2;
}

// W_hh [3H][H] fp32 -> fragment-linear bf16: Wv[blk][g][ks][lane][8]
__global__ __launch_bounds__(128) void cvt_whh_frag(const float* __restrict__ W,
                                                    unsigned short* __restrict__ Wv) {
  int r = blockIdx.x;              // 0..3071
  int g = r >> 10, i = r & 1023, blk = i >> 4, il = i & 15;
  int q = threadIdx.x;             // 8-elem chunk 0..127
  int ks = q >> 2, ksub = q & 3, lane = il + ksub * 16;
  f32x4 v0 = *(const f32x4*)(W + (size_t)r * HID + q * 8);
  f32x4 v1 = *(const f32x4*)(W + (size_t)r * HID + q * 8 + 4);
  u16x8 o;
  o[0]=f2bf(v0[0]); o[1]=f2bf(v0[1]); o[2]=f2bf(v0[2]); o[3]=f2bf(v0[3]);
  o[4]=f2bf(v1[0]); o[5]=f2bf(v1[1]); o[6]=f2bf(v1[2]); o[7]=f2bf(v1[3]);
  size_t dst = ((((size_t)blk * 3 + g) * 32 + ks) * 64 + lane) * 8;
  *(u16x8*)(Wv + dst) = o;
}

__global__ __launch_bounds__(256) void gather_embed(const int* __restrict__ seqs,
                                                    const float* __restrict__ emb,
                                                    unsigned short* __restrict__ Aout,
                                                    int relu) {
  int r = blockIdx.x, q = threadIdx.x;
  int tok = seqs[r];
  f32x4 v = *(const f32x4*)(emb + (size_t)tok * HID + q * 4);
  if (relu) {
    v[0]=fmaxf(v[0],0.f); v[1]=fmaxf(v[1],0.f); v[2]=fmaxf(v[2],0.f); v[3]=fmaxf(v[3],0.f);
  }
  u16x4 o; o[0]=f2bf(v[0]); o[1]=f2bf(v[1]); o[2]=f2bf(v[2]); o[3]=f2bf(v[3]);
  *(u16x4*)(Aout + (size_t)r * HID + q * 4) = o;
}

// relu(thought) -> bf16, rows 32..127 zero-padded
__global__ __launch_bounds__(256) void gather_thought(const float* __restrict__ hfin,
                                                      unsigned short* __restrict__ Aout) {
  int r = blockIdx.x, q = threadIdx.x;
  u16x4 o = {0, 0, 0, 0};
  if (r < NB) {
    f32x4 v = *(const f32x4*)(hfin + (size_t)r * HID + q * 4);
    o[0]=f2bf(fmaxf(v[0],0.f)); o[1]=f2bf(fmaxf(v[1],0.f));
    o[2]=f2bf(fmaxf(v[2],0.f)); o[3]=f2bf(fmaxf(v[3],0.f));
  }
  *(u16x4*)(Aout + (size_t)r * HID + q * 4) = o;
}

__global__ __launch_bounds__(256) void zero_f32(float* __restrict__ p) {
  p[blockIdx.x * 256 + threadIdx.x] = 0.f;
}

// ---------------- bf16 MFMA GEMM: C = A[M,1024] * B[N,1024]^T (+ epilogue) ----------------
// 128x128 tile, BK=32, global_load_lds width-16 staging (m97 structure).
// 1-D grid; XCD-chunked swizzle + (MT x 4) supertile.
template<int MODE, int MT>
__global__ __launch_bounds__(256) void gemm_bf16(const unsigned short* __restrict__ A,
                                                 const unsigned short* __restrict__ Bw,
                                                 const float* __restrict__ bias,
                                                 const float* __restrict__ add2,
                                                 float* __restrict__ out, int N) {
  __shared__ unsigned short Abuf[128 * 32];
  __shared__ unsigned short Bbuf[128 * 32];
  const int K = HID;
  int tid = threadIdx.x, lane = tid & 63, wid = tid >> 6;
  int nwg = gridDim.x;
  int u = (blockIdx.x & 7) * (nwg >> 3) + (blockIdx.x >> 3);
  int g = u / (MT * 4);
  int r_ = u - g * (MT * 4);
  int bm = r_ % MT;
  int bn = g * 4 + r_ / MT;
  int wrow = wid >> 1, wcol = wid & 1;
  f32x4 zero4 = {0.f, 0.f, 0.f, 0.f};
  f32x4 acc[4][4];
#pragma unroll
  for (int i = 0; i < 4; ++i)
#pragma unroll
    for (int j = 0; j < 4; ++j) acc[i][j] = zero4;

  int srow = tid >> 2, spart = tid & 3;
  const unsigned short* Ag = A + ((size_t)bm * 128 + srow) * K + spart * 8;
  const unsigned short* Bg = Bw + ((size_t)bn * 128 + srow) * K + spart * 8;
  unsigned short* As = Abuf + tid * 8;       // linear: lane*16B within wave
  unsigned short* Bs = Bbuf + tid * 8;

  for (int ks = 0; ks < 32; ++ks) {
    int k0 = ks * 32;
    __syncthreads();                          // prev MFMA ds_reads done
    gld_lds16(Ag + k0, As);
    gld_lds16(Ag + (size_t)64 * K + k0, As + 64 * 32);
    gld_lds16(Bg + k0, Bs);
    gld_lds16(Bg + (size_t)64 * K + k0, Bs + 64 * 32);
    __syncthreads();                          // vmcnt(0) drain -> LDS valid
    bf16x8 af[4], bfr[4];
#pragma unroll
    for (int mi = 0; mi < 4; ++mi) {
      BfPun tpun;
      tpun.u = *(const u16x8*)(Abuf + (wrow * 64 + mi * 16 + (lane & 15)) * 32 + (lane >> 4) * 8);
      af[mi] = tpun.b;
    }
#pragma unroll
    for (int ni = 0; ni < 4; ++ni) {
      BfPun tpun;
      tpun.u = *(const u16x8*)(Bbuf + (wcol * 64 + ni * 16 + (lane & 15)) * 32 + (lane >> 4) * 8);
      bfr[ni] = tpun.b;
    }
#pragma unroll
    for (int mi = 0; mi < 4; ++mi)
#pragma unroll
      for (int ni = 0; ni < 4; ++ni)
        acc[mi][ni] = __builtin_amdgcn_mfma_f32_16x16x32_bf16(af[mi], bfr[ni], acc[mi][ni], 0, 0, 0);
  }

#pragma unroll
  for (int mi = 0; mi < 4; ++mi) {
    int rb = bm * 128 + wrow * 64 + mi * 16 + ((lane >> 4) << 2);
#pragma unroll
    for (int ni = 0; ni < 4; ++ni) {
      int c = bn * 128 + wcol * 64 + ni * 16 + (lane & 15);
#pragma unroll
      for (int e = 0; e < 4; ++e) {
        int r = rb + e;
        float v = acc[mi][ni][e];
        if (MODE == 0) {
          out[(size_t)r * N + c] = v + bias[c];
        } else if (MODE == 1) {
          int t = r & 63, b = r >> 6;
          int gg = c >> 10, ci = c & 1023;
          out[(((size_t)t * 3 + gg) * NB + b) * HID + ci] = v + bias[c];
        } else if (MODE == 2) {
          int t = r & 63, b = r >> 6;
          int gg = c >> 10, ci = c & 1023;
          out[(((size_t)t * 3 + gg) * NB + b) * HID + ci] = v + add2[(size_t)b * G3 + c];
        } else {
          int b = r & 31, t = r >> 5;
          out[((size_t)b * TLEN + t) * VOCAB + c] = v + bias[c];
        }
      }
    }
  }
}

// ---------------- persistent GRU scan (MFMA, fragment-linear layouts) ----------------
// 64 blocks x 384 threads (6 waves = 3 gates x 2 batch-halves).
// Cross-block sync: per-step 8 sub-counters (64 B apart; blocks blk&7 -> counter)
// -- splits the same-address RMW chain 8x; single wave polls all 8 (lane&7).
__global__ __launch_bounds__(384, 1) void gru_scan(
    const unsigned short* __restrict__ Wv,   // [64][3][32][64][8] bf16
    const float* __restrict__ b_hh,
    const float* __restrict__ xpT,           // [T][3][NB][HID]
    unsigned short* __restrict__ hbx,        // [nsteps][2][32][64][8] write-once
    const int* __restrict__ lens,            // null => no freeze (decoder)
    unsigned short* __restrict__ hs_out,     // null for encoder; [T*NB][HID] bf16
    float* __restrict__ hfin,                // final h fp32 (encoder) or null
    int* __restrict__ bar, int nsteps) {     // bar[(t*8+i)*16], zeroed per launch
  __shared__ unsigned short Wlds[49152];     // 96 KB
  __shared__ float gh[48][33];
  __shared__ float h32[32][16];
  __shared__ float bhh_s[48];
  __shared__ int   lens_s[32];
  int tid = threadIdx.x, lane = tid & 63, w = tid >> 6;
  int g = w >> 1, part = w & 1;
  int blk = blockIdx.x, i0 = blk * 16;

  if (tid < 32) lens_s[tid] = lens ? lens[tid] : 0x7fffffff;
  if (tid >= 64 && tid < 112) {
    int q = tid - 64;
    bhh_s[q] = b_hh[(size_t)(q >> 4) * HID + i0 + (q & 15)];
  }
  if (tid < 256) h32[tid >> 3][((tid & 7) * 2)] = 0.f;
  if (tid < 256) h32[tid >> 3][((tid & 7) * 2) + 1] = 0.f;

  // stage W fragment slice into LDS (one time)
  {
    const unsigned short* Wsrc = Wv + (size_t)blk * 49152;
    for (int j = tid; j < 6144; j += 384)
      *(u16x8*)(Wlds + (size_t)j * 8) = *(const u16x8*)(Wsrc + (size_t)j * 8);
  }
  __syncthreads();

  int eb = tid >> 3, eil = (tid & 7) * 2;
  f32x2 xr2, xz2, xn2;

  for (int t = 0; t < nsteps; ++t) {
    // xp loads for step t: issued first, complete under the MFMA phase
    if (tid < 256) {
      const float* xb = xpT + ((size_t)t * 3 * NB + eb) * HID + i0 + eil;
      xr2 = *(const f32x2*)(xb);
      xz2 = *(const f32x2*)(xb + (size_t)NB * HID);
      xn2 = *(const f32x2*)(xb + (size_t)2 * NB * HID);
    }
    f32x4 acc = {0.f, 0.f, 0.f, 0.f};
    if (t > 0) {
      const unsigned short* hp = hbx + (size_t)(t - 1) * 32768 + part * 16384 + lane * 8;
      u32x4 pb[16];
#pragma unroll
      for (int j = 0; j < 16; ++j) pb[j] = *(const u32x4*)(hp + (size_t)j * 512);
#pragma unroll
      for (int ks = 0; ks < 32; ++ks) {
        BfPun a_;
        a_.u = *(const u16x8*)(Wlds + ((size_t)(g * 32 + ks) * 64 + lane) * 8);
        CvPun cv; cv.u = pb[ks & 15];
        if (ks + 16 < 32) pb[ks & 15] = *(const u32x4*)(hp + (size_t)(ks + 16) * 512);
        acc = __builtin_amdgcn_mfma_f32_16x16x32_bf16(a_.b, cv.b, acc, 0, 0, 0);
      }
    }
    {
      int il4 = (lane >> 4) * 4, cb = part * 16 + (lane & 15);
#pragma unroll
      for (int e = 0; e < 4; ++e) gh[g * 16 + il4 + e][cb] = acc[e];
    }
    __syncthreads();

    if (tid < 256) {
      float sr0 = gh[eil][eb],      sr1 = gh[eil + 1][eb];
      float sz0 = gh[16 + eil][eb], sz1 = gh[16 + eil + 1][eb];
      float sn0 = gh[32 + eil][eb], sn1 = gh[32 + eil + 1][eb];
      float rg0 = sig_f(xr2[0] + sr0 + bhh_s[eil]);
      float rg1 = sig_f(xr2[1] + sr1 + bhh_s[eil + 1]);
      float zg0 = sig_f(xz2[0] + sz0 + bhh_s[16 + eil]);
      float zg1 = sig_f(xz2[1] + sz1 + bhh_s[16 + eil + 1]);
      float ng0 = tanh_f(xn2[0] + rg0 * (sn0 + bhh_s[32 + eil]));
      float ng1 = tanh_f(xn2[1] + rg1 * (sn1 + bhh_s[32 + eil + 1]));
      float h0o = h32[eb][eil], h1o = h32[eb][eil + 1];
      float hn0 = (1.f - zg0) * ng0 + zg0 * h0o;
      float hn1 = (1.f - zg1) * ng1 + zg1 * h1o;
      if (t >= lens_s[eb]) { hn0 = h0o; hn1 = h1o; }   // packed-seq freeze
      h32[eb][eil] = hn0; h32[eb][eil + 1] = hn1;
      unsigned int pk = (unsigned int)f2bf(hn0) | ((unsigned int)f2bf(hn1) << 16);
      int k = i0 + eil;
      int ksf = k >> 5, lnf = (eb & 15) + ((k >> 3) & 3) * 16, sub = k & 7;
      unsigned short* dst = hbx + (size_t)t * 32768 + (size_t)(eb >> 4) * 16384
                            + (size_t)ksf * 512 + lnf * 8 + sub;
      __hip_atomic_store((unsigned int*)dst, pk, __ATOMIC_RELAXED, __HIP_MEMORY_SCOPE_AGENT);
      if (hs_out)
        *(unsigned int*)(hs_out + ((size_t)t * NB + eb) * HID + k) = pk;
    }

    if (t + 1 < nsteps) {
      __syncthreads();   // vmcnt(0) drain: this block's hbx stores visible at L3
      if (tid == 0)
        __hip_atomic_fetch_add(&bar[(t * 8 + (blk & 7)) * 16], 1,
                               __ATOMIC_RELAXED, __HIP_MEMORY_SCOPE_AGENT);
      if (tid < 64) {
        const int* cp = &bar[(t * 8 + (lane & 7)) * 16];
        while (__hip_atomic_load(cp, __ATOMIC_RELAXED, __HIP_MEMORY_SCOPE_AGENT) < 8)
          __builtin_amdgcn_s_sleep(1);
      }
      __syncthreads();   // all h(t) visible; step t+1 loads ordered after poll
    }
  }

  if (hfin && tid < 256) {
    f32x2 hv; hv[0] = h32[eb][eil]; hv[1] = h32[eb][eil + 1];
    *(f32x2*)(hfin + (size_t)eb * HID + i0 + eil) = hv;
  }
}

// ---------------- LDS-staged in-place row log_softmax on d_out [2048 x 32000] ----------------
__global__ __launch_bounds__(1024, 1) void log_softmax_lds(float* __restrict__ out) {
  __shared__ float rowbuf[VOCAB];            // 128000 B
  __shared__ float ms[16], ss[16];
  size_t row = blockIdx.x;
  float* p = out + row * VOCAB;
  const f32x4* p4 = (const f32x4*)p;
  int tid = threadIdx.x;
  float m = -3.0e38f, s = 0.f;
  for (int j = tid; j < VOCAB / 4; j += 1024) {
    f32x4 v = p4[j];
    *(f32x4*)(rowbuf + j * 4) = v;
#pragma unroll
    for (int e = 0; e < 4; ++e) {
      float x = v[e];
      float nm = fmaxf(m, x);
      s = s * __expf(m - nm) + __expf(x - nm);
      m = nm;
    }
  }
#pragma unroll
  for (int off = 1; off < 64; off <<= 1) {
    float m2 = __shfl_xor(m, off, 64);
    float s2 = __shfl_xor(s, off, 64);
    float nm = fmaxf(m, m2);
    s = s * __expf(m - nm) + s2 * __expf(m2 - nm);
    m = nm;
  }
  if ((tid & 63) == 0) { ms[tid >> 6] = m; ss[tid >> 6] = s; }
  __syncthreads();
  float M = -3.0e38f;
#pragma unroll
  for (int i = 0; i < 16; ++i) M = fmaxf(M, ms[i]);
  float S = 0.f;
#pragma unroll
  for (int i = 0; i < 16; ++i) S += ss[i] * __expf(ms[i] - M);
  float lse = M + __logf(S);
  f32x4* o4 = (f32x4*)p;
  for (int j = tid; j < VOCAB / 4; j += 1024) {
    f32x4 v = *(const f32x4*)(rowbuf + j * 4);
    v[0] -= lse; v[1] -= lse; v[2] -= lse; v[3] -= lse;
    o4[j] = v;
  }
}

// ---------------- host ----------------

extern "C" void kernel_launch(void* const* d_in, const int* in_sizes, int n_in,
                              void* d_out, int out_size, void* d_ws, size_t ws_size,
                              hipStream_t stream) {
  (void)in_sizes; (void)n_in; (void)out_size; (void)ws_size;
  const int*   input_seqs  = (const int*)d_in[0];
  const int*   target_seqs = (const int*)d_in[1];
  const int*   input_lens  = (const int*)d_in[2];
  const float* emb_enc = (const float*)d_in[3];
  const float* W_ih_e  = (const float*)d_in[4];
  const float* W_hh_e  = (const float*)d_in[5];
  const float* b_ih_e  = (const float*)d_in[6];
  const float* b_hh_e  = (const float*)d_in[7];
  const float* emb_dec = (const float*)d_in[8];
  const float* W_ih_d  = (const float*)d_in[9];
  const float* W_hh_d  = (const float*)d_in[10];
  const float* b_ih_d  = (const float*)d_in[11];
  const float* b_hh_d  = (const float*)d_in[12];
  const float* W_out   = (const float*)d_in[13];
  const float* b_out   = (const float*)d_in[14];
  float* out = (float*)d_out;

  char* p = (char*)d_ws;
  auto take = [&](size_t n) { char* q = p; p += (n + 255) & ~(size_t)255; return q; };
  unsigned short* Wbf_e  = (unsigned short*)take((size_t)G3 * HID * 2);
  unsigned short* Wbf_1d = (unsigned short*)take((size_t)G3 * HID * 2);
  unsigned short* Wbf_2d = (unsigned short*)take((size_t)G3 * HID * 2);
  unsigned short* Wbf_o  = (unsigned short*)take((size_t)VOCAB * HID * 2);
  unsigned short* Wv_e   = (unsigned short*)take((size_t)G3 * HID * 2);
  unsigned short* Wv_d   = (unsigned short*)take((size_t)G3 * HID * 2);
  unsigned short* A_ed   = (unsigned short*)take((size_t)2048 * HID * 2);
  unsigned short* A_th   = (unsigned short*)take((size_t)128 * HID * 2);
  unsigned short* A_hs   = (unsigned short*)take((size_t)2048 * HID * 2);
  float* xpT = (float*)take((size_t)64 * 3 * NB * HID * 4);
  float* t2  = (float*)take((size_t)128 * G3 * 4);
  unsigned short* hbx_e = (unsigned short*)take((size_t)SLEN * NB * HID * 2);
  unsigned short* hbx_d = (unsigned short*)take((size_t)TLEN * NB * HID * 2);
  int*   bar_e = (int*)take((size_t)SLEN * 8 * 16 * 4);   // 8 sub-counters/step, 64B apart
  int*   bar_d = (int*)take((size_t)TLEN * 8 * 16 * 4);
  float* hfin = (float*)take((size_t)NB * HID * 4);

  // weight converts (fp32 -> bf16)
  cvt_bf16<<<dim3((G3 * HID) / 1024), 256, 0, stream>>>(W_ih_e, Wbf_e);
  cvt_split_d<<<dim3(G3), 256, 0, stream>>>(W_ih_d, Wbf_1d, Wbf_2d);
  cvt_bf16<<<dim3((VOCAB * HID) / 1024), 256, 0, stream>>>(W_out, Wbf_o);
  cvt_whh_frag<<<dim3(G3), 128, 0, stream>>>(W_hh_e, Wv_e);
  cvt_whh_frag<<<dim3(G3), 128, 0, stream>>>(W_hh_d, Wv_d);
  zero_f32<<<dim3(64), 256, 0, stream>>>((float*)bar_e);   // bar_e + bar_d (64 KB)

  // ---- encoder ----
  gather_embed<<<dim3(NB * SLEN), 256, 0, stream>>>(input_seqs, emb_enc, A_ed, 0);
  gemm_bf16<1, 16><<<dim3(384), 256, 0, stream>>>(A_ed, Wbf_e, b_ih_e, nullptr, xpT, G3);
  gru_scan<<<dim3(64), 384, 0, stream>>>(Wv_e, b_hh_e, xpT, hbx_e, input_lens,
                                         nullptr, hfin, bar_e, SLEN);

  // ---- decoder pre ----
  gather_thought<<<dim3(128), 256, 0, stream>>>(hfin, A_th);
  gemm_bf16<0, 1><<<dim3(24), 256, 0, stream>>>(A_th, Wbf_2d, b_ih_d, nullptr, t2, G3);
  gather_embed<<<dim3(NB * TLEN), 256, 0, stream>>>(target_seqs, emb_dec, A_ed, 1);
  gemm_bf16<2, 16><<<dim3(384), 256, 0, stream>>>(A_ed, Wbf_1d, nullptr, t2, xpT, G3);

  // ---- decoder scan ----
  gru_scan<<<dim3(64), 384, 0, stream>>>(Wv_d, b_hh_d, xpT, hbx_d, nullptr,
                                         A_hs, nullptr, bar_d, TLEN);

  // ---- logits (direct to d_out) + in-place log_softmax ----
  gemm_bf16<3, 16><<<dim3(4000), 256, 0, stream>>>(A_hs, Wbf_o, b_out, nullptr, out, VOCAB);
  log_softmax_lds<<<dim3(NB * TLEN), 1024, 0, stream>>>(out);
}

// Round 9
// 870.420 us; speedup vs baseline: 1.2530x; 1.0252x over previous
//
#include <hip/hip_runtime.h>
#include <stdint.h>
#include <stddef.h>

#define VOCAB 32000
#define HID   1024
#define NB    32
#define SLEN  64
#define TLEN  64
#define G3    3072

typedef float          f32x4  __attribute__((ext_vector_type(4)));
typedef float          f32x2  __attribute__((ext_vector_type(2)));
typedef __bf16         bf16x8 __attribute__((ext_vector_type(8)));
typedef unsigned short u16x8  __attribute__((ext_vector_type(8)));
typedef unsigned short u16x4  __attribute__((ext_vector_type(4)));
typedef unsigned int   u32x4  __attribute__((ext_vector_type(4)));

union BfPun { u16x8 u; bf16x8 b; };
union CvPun { u32x4 u; bf16x8 b; };

__device__ __forceinline__ unsigned short f2bf(float f) {
  unsigned int u = __builtin_bit_cast(unsigned int, f);
  u += 0x7FFFu + ((u >> 16) & 1u);   // RNE round to bf16
  return (unsigned short)(u >> 16);
}
__device__ __forceinline__ float bf2f(unsigned short h) {
  unsigned int u = (unsigned int)h << 16;
  return __builtin_bit_cast(float, u);
}

// fast sigmoid / tanh via v_exp + v_rcp
__device__ __forceinline__ float sig_f(float x) {
  return __builtin_amdgcn_rcpf(1.f + __expf(-x));
}
__device__ __forceinline__ float tanh_f(float x) {
  return 2.f * __builtin_amdgcn_rcpf(1.f + __expf(-2.f * x)) - 1.f;
}

// async global -> LDS, 16 B per lane (LDS dest must be wave-uniform base + lane*16)
__device__ __forceinline__ void gld_lds16(const unsigned short* g, unsigned short* l) {
  __builtin_amdgcn_global_load_lds(
      (const __attribute__((address_space(1))) unsigned int*)g,
      (__attribute__((address_space(3))) unsigned int*)l,
      16, 0, 0);
}

// ---------------- converts / gathers / init ----------------

__global__ __launch_bounds__(256) void cvt_bf16(const float* __restrict__ in,
                                                unsigned short* __restrict__ out) {
  size_t idx = ((size_t)blockIdx.x * 256 + threadIdx.x) * 4;
  f32x4 v = *(const f32x4*)(in + idx);
  u16x4 o;
  o[0] = f2bf(v[0]); o[1] = f2bf(v[1]); o[2] = f2bf(v[2]); o[3] = f2bf(v[3]);
  *(u16x4*)(out + idx) = o;
}

// W_ih_d [3072][2048] -> W1 (cols 0..1023), W2 (cols 1024..2047), both bf16 [3072][1024]
__global__ __launch_bounds__(256) void cvt_split_d(const float* __restrict__ Wd,
                                                   unsigned short* __restrict__ W1,
                                                   unsigned short* __restrict__ W2) {
  int r = blockIdx.x, q = threadIdx.x;
  const float* src = Wd + (size_t)r * 2048;
  f32x4 v1 = *(const f32x4*)(src + q * 4);
  f32x4 v2 = *(const f32x4*)(src + 1024 + q * 4);
  u16x4 o1, o2;
  o1[0]=f2bf(v1[0]); o1[1]=f2bf(v1[1]); o1[2]=f2bf(v1[2]); o1[3]=f2bf(v1[3]);
  o2[0]=f2bf(v2[0]); o2[1]=f2bf(v2[1]); o2[2]=f2bf(v2[2]); o2[3]=f2bf(v2[3]);
  *(u16x4*)(W1 + (size_t)r * 1024 + q * 4) = o1;
  *(u16x4*)(W2 + (size_t)r * 1024 + q * 4) = o2;
}

// W_hh [3H][H] fp32 -> fragment-linear bf16: Wv[blk][g][ks][lane][8]
__global__ __launch_bounds__(128) void cvt_whh_frag(const float* __restrict__ W,
                                                    unsigned short* __restrict__ Wv) {
  int r = blockIdx.x;              // 0..3071
  int g = r >> 10, i = r & 1023, blk = i >> 4, il = i & 15;
  int q = threadIdx.x;             // 8-elem chunk 0..127
  int ks = q >> 2, ksub = q & 3, lane = il + ksub * 16;
  f32x4 v0 = *(const f32x4*)(W + (size_t)r * HID + q * 8);
  f32x4 v1 = *(const f32x4*)(W + (size_t)r * HID + q * 8 + 4);
  u16x8 o;
  o[0]=f2bf(v0[0]); o[1]=f2bf(v0[1]); o[2]=f2bf(v0[2]); o[3]=f2bf(v0[3]);
  o[4]=f2bf(v1[0]); o[5]=f2bf(v1[1]); o[6]=f2bf(v1[2]); o[7]=f2bf(v1[3]);
  size_t dst = ((((size_t)blk * 3 + g) * 32 + ks) * 64 + lane) * 8;
  *(u16x8*)(Wv + dst) = o;
}

__global__ __launch_bounds__(256) void gather_embed(const int* __restrict__ seqs,
                                                    const float* __restrict__ emb,
                                                    unsigned short* __restrict__ Aout,
                                                    int relu) {
  int r = blockIdx.x, q = threadIdx.x;
  int tok = seqs[r];
  f32x4 v = *(const f32x4*)(emb + (size_t)tok * HID + q * 4);
  if (relu) {
    v[0]=fmaxf(v[0],0.f); v[1]=fmaxf(v[1],0.f); v[2]=fmaxf(v[2],0.f); v[3]=fmaxf(v[3],0.f);
  }
  u16x4 o; o[0]=f2bf(v[0]); o[1]=f2bf(v[1]); o[2]=f2bf(v[2]); o[3]=f2bf(v[3]);
  *(u16x4*)(Aout + (size_t)r * HID + q * 4) = o;
}

// relu(thought) -> bf16, rows 32..127 zero-padded
__global__ __launch_bounds__(256) void gather_thought(const float* __restrict__ hfin,
                                                      unsigned short* __restrict__ Aout) {
  int r = blockIdx.x, q = threadIdx.x;
  u16x4 o = {0, 0, 0, 0};
  if (r < NB) {
    f32x4 v = *(const f32x4*)(hfin + (size_t)r * HID + q * 4);
    o[0]=f2bf(fmaxf(v[0],0.f)); o[1]=f2bf(fmaxf(v[1],0.f));
    o[2]=f2bf(fmaxf(v[2],0.f)); o[3]=f2bf(fmaxf(v[3],0.f));
  }
  *(u16x4*)(Aout + (size_t)r * HID + q * 4) = o;
}

__global__ __launch_bounds__(256) void zero_f32(float* __restrict__ p) {
  p[blockIdx.x * 256 + threadIdx.x] = 0.f;
}

// ---------------- bf16 MFMA GEMM: C = A[M,1024] * B[N,1024]^T (+ epilogue) ----------------
// 128x128 tile, BK=64, global_load_lds width-16 staging, involution chunk-swizzle:
//   LDS[row][c8] holds global chunk (c8 ^ (row&7)) -> ds_read 2-way conflict-free.
// 1-D grid; XCD-chunked swizzle + (MT x 4) supertile.
// MODE 0/1/2 write fp32 (xp projections); MODE 3 writes bf16 logits into the
// first 64000 B of each output row's 128000 B slot in d_out.
template<int MODE, int MT>
__global__ __launch_bounds__(256) void gemm_bf16(const unsigned short* __restrict__ A,
                                                 const unsigned short* __restrict__ Bw,
                                                 const float* __restrict__ bias,
                                                 const float* __restrict__ add2,
                                                 void* __restrict__ outv, int N) {
  __shared__ unsigned short Abuf[128 * 64];
  __shared__ unsigned short Bbuf[128 * 64];
  const int K = HID;
  int tid = threadIdx.x, lane = tid & 63, wid = tid >> 6;
  int nwg = gridDim.x;
  int u = (blockIdx.x & 7) * (nwg >> 3) + (blockIdx.x >> 3);
  int g = u / (MT * 4);
  int r_ = u - g * (MT * 4);
  int bm = r_ % MT;
  int bn = g * 4 + r_ / MT;
  int wrow = wid >> 1, wcol = wid & 1;
  f32x4 zero4 = {0.f, 0.f, 0.f, 0.f};
  f32x4 acc[4][4];
#pragma unroll
  for (int i = 0; i < 4; ++i)
#pragma unroll
    for (int j = 0; j < 4; ++j) acc[i][j] = zero4;

  // staging: pass j covers rows j*32+(tid>>3), source chunk pre-swizzled
  int srow = tid >> 3;                       // 0..31
  int csrc = (tid & 7) ^ (srow & 7);         // involution, constant per thread
  const unsigned short* Ag = A + ((size_t)bm * 128 + srow) * K + csrc * 8;
  const unsigned short* Bg = Bw + ((size_t)bn * 128 + srow) * K + csrc * 8;
  unsigned short* As = Abuf + tid * 8;       // linear LDS dest (lane*16B per wave)
  unsigned short* Bs = Bbuf + tid * 8;

  // frag read chunk indices (swizzled): row&7 == lane&7 (16-row tiles, 8|16)
  int ca0 = (0 * 4 + (lane >> 4)) ^ (lane & 7);   // kk=0
  int ca1 = (1 * 4 + (lane >> 4)) ^ (lane & 7);   // kk=1

  for (int ks = 0; ks < 16; ++ks) {
    size_t k0 = ks * 64;
    __syncthreads();                          // prev MFMA ds_reads done
#pragma unroll
    for (int j = 0; j < 4; ++j)
      gld_lds16(Ag + (size_t)j * 32 * K + k0, As + j * 2048);
#pragma unroll
    for (int j = 0; j < 4; ++j)
      gld_lds16(Bg + (size_t)j * 32 * K + k0, Bs + j * 2048);
    __syncthreads();                          // vmcnt(0) drain -> LDS valid
#pragma unroll
    for (int kk = 0; kk < 2; ++kk) {
      int cc = kk ? ca1 : ca0;
      bf16x8 af[4], bfr[4];
#pragma unroll
      for (int mi = 0; mi < 4; ++mi) {
        BfPun tpun;
        tpun.u = *(const u16x8*)(Abuf + (wrow * 64 + mi * 16 + (lane & 15)) * 64 + cc * 8);
        af[mi] = tpun.b;
      }
#pragma unroll
      for (int ni = 0; ni < 4; ++ni) {
        BfPun tpun;
        tpun.u = *(const u16x8*)(Bbuf + (wcol * 64 + ni * 16 + (lane & 15)) * 64 + cc * 8);
        bfr[ni] = tpun.b;
      }
#pragma unroll
      for (int mi = 0; mi < 4; ++mi)
#pragma unroll
        for (int ni = 0; ni < 4; ++ni)
          acc[mi][ni] = __builtin_amdgcn_mfma_f32_16x16x32_bf16(af[mi], bfr[ni], acc[mi][ni], 0, 0, 0);
    }
  }

  float* out = (float*)outv;
  unsigned short* o16 = (unsigned short*)outv;
#pragma unroll
  for (int mi = 0; mi < 4; ++mi) {
    int rb = bm * 128 + wrow * 64 + mi * 16 + ((lane >> 4) << 2);
#pragma unroll
    for (int ni = 0; ni < 4; ++ni) {
      int c = bn * 128 + wcol * 64 + ni * 16 + (lane & 15);
#pragma unroll
      for (int e = 0; e < 4; ++e) {
        int r = rb + e;
        float v = acc[mi][ni][e];
        if (MODE == 0) {
          out[(size_t)r * N + c] = v + bias[c];
        } else if (MODE == 1) {
          int t = r & 63, b = r >> 6;
          int gg = c >> 10, ci = c & 1023;
          out[(((size_t)t * 3 + gg) * NB + b) * HID + ci] = v + bias[c];
        } else if (MODE == 2) {
          int t = r & 63, b = r >> 6;
          int gg = c >> 10, ci = c & 1023;
          out[(((size_t)t * 3 + gg) * NB + b) * HID + ci] = v + add2[(size_t)b * G3 + c];
        } else {
          int b = r & 31, t = r >> 5;
          // bf16 logits into the head of row (b*64+t)'s fp32 slot (64000 u16 stride)
          o16[(size_t)(b * 64 + t) * (VOCAB * 2) + c] = f2bf(v + bias[c]);
        }
      }
    }
  }
}

// ---------------- persistent GRU scan (MFMA, fragment-linear layouts) ----------------
// 64 blocks x 384 threads (6 waves = 3 gates x 2 batch-halves).
// Cross-block sync: per-step 8 sub-counters (64 B apart; blocks blk&7 -> counter).
__global__ __launch_bounds__(384, 1) void gru_scan(
    const unsigned short* __restrict__ Wv,   // [64][3][32][64][8] bf16
    const float* __restrict__ b_hh,
    const float* __restrict__ xpT,           // [T][3][NB][HID]
    unsigned short* __restrict__ hbx,        // [nsteps][2][32][64][8] write-once
    const int* __restrict__ lens,            // null => no freeze (decoder)
    unsigned short* __restrict__ hs_out,     // null for encoder; [T*NB][HID] bf16
    float* __restrict__ hfin,                // final h fp32 (encoder) or null
    int* __restrict__ bar, int nsteps) {     // bar[(t*8+i)*16], zeroed per launch
  __shared__ unsigned short Wlds[49152];     // 96 KB
  __shared__ float gh[48][33];
  __shared__ float h32[32][16];
  __shared__ float bhh_s[48];
  __shared__ int   lens_s[32];
  int tid = threadIdx.x, lane = tid & 63, w = tid >> 6;
  int g = w >> 1, part = w & 1;
  int blk = blockIdx.x, i0 = blk * 16;

  if (tid < 32) lens_s[tid] = lens ? lens[tid] : 0x7fffffff;
  if (tid >= 64 && tid < 112) {
    int q = tid - 64;
    bhh_s[q] = b_hh[(size_t)(q >> 4) * HID + i0 + (q & 15)];
  }
  if (tid < 256) h32[tid >> 3][((tid & 7) * 2)] = 0.f;
  if (tid < 256) h32[tid >> 3][((tid & 7) * 2) + 1] = 0.f;

  // stage W fragment slice into LDS (one time)
  {
    const unsigned short* Wsrc = Wv + (size_t)blk * 49152;
    for (int j = tid; j < 6144; j += 384)
      *(u16x8*)(Wlds + (size_t)j * 8) = *(const u16x8*)(Wsrc + (size_t)j * 8);
  }
  __syncthreads();

  int eb = tid >> 3, eil = (tid & 7) * 2;
  f32x2 xr2, xz2, xn2;

  for (int t = 0; t < nsteps; ++t) {
    // xp loads for step t: issued first, complete under the MFMA phase
    if (tid < 256) {
      const float* xb = xpT + ((size_t)t * 3 * NB + eb) * HID + i0 + eil;
      xr2 = *(const f32x2*)(xb);
      xz2 = *(const f32x2*)(xb + (size_t)NB * HID);
      xn2 = *(const f32x2*)(xb + (size_t)2 * NB * HID);
    }
    f32x4 acc = {0.f, 0.f, 0.f, 0.f};
    if (t > 0) {
      const unsigned short* hp = hbx + (size_t)(t - 1) * 32768 + part * 16384 + lane * 8;
      u32x4 pb[16];
#pragma unroll
      for (int j = 0; j < 16; ++j) pb[j] = *(const u32x4*)(hp + (size_t)j * 512);
#pragma unroll
      for (int ks = 0; ks < 32; ++ks) {
        BfPun a_;
        a_.u = *(const u16x8*)(Wlds + ((size_t)(g * 32 + ks) * 64 + lane) * 8);
        CvPun cv; cv.u = pb[ks & 15];
        if (ks + 16 < 32) pb[ks & 15] = *(const u32x4*)(hp + (size_t)(ks + 16) * 512);
        acc = __builtin_amdgcn_mfma_f32_16x16x32_bf16(a_.b, cv.b, acc, 0, 0, 0);
      }
    }
    {
      int il4 = (lane >> 4) * 4, cb = part * 16 + (lane & 15);
#pragma unroll
      for (int e = 0; e < 4; ++e) gh[g * 16 + il4 + e][cb] = acc[e];
    }
    __syncthreads();

    if (tid < 256) {
      float sr0 = gh[eil][eb],      sr1 = gh[eil + 1][eb];
      float sz0 = gh[16 + eil][eb], sz1 = gh[16 + eil + 1][eb];
      float sn0 = gh[32 + eil][eb], sn1 = gh[32 + eil + 1][eb];
      float rg0 = sig_f(xr2[0] + sr0 + bhh_s[eil]);
      float rg1 = sig_f(xr2[1] + sr1 + bhh_s[eil + 1]);
      float zg0 = sig_f(xz2[0] + sz0 + bhh_s[16 + eil]);
      float zg1 = sig_f(xz2[1] + sz1 + bhh_s[16 + eil + 1]);
      float ng0 = tanh_f(xn2[0] + rg0 * (sn0 + bhh_s[32 + eil]));
      float ng1 = tanh_f(xn2[1] + rg1 * (sn1 + bhh_s[32 + eil + 1]));
      float h0o = h32[eb][eil], h1o = h32[eb][eil + 1];
      float hn0 = (1.f - zg0) * ng0 + zg0 * h0o;
      float hn1 = (1.f - zg1) * ng1 + zg1 * h1o;
      if (t >= lens_s[eb]) { hn0 = h0o; hn1 = h1o; }   // packed-seq freeze
      h32[eb][eil] = hn0; h32[eb][eil + 1] = hn1;
      unsigned int pk = (unsigned int)f2bf(hn0) | ((unsigned int)f2bf(hn1) << 16);
      int k = i0 + eil;
      int ksf = k >> 5, lnf = (eb & 15) + ((k >> 3) & 3) * 16, sub = k & 7;
      unsigned short* dst = hbx + (size_t)t * 32768 + (size_t)(eb >> 4) * 16384
                            + (size_t)ksf * 512 + lnf * 8 + sub;
      __hip_atomic_store((unsigned int*)dst, pk, __ATOMIC_RELAXED, __HIP_MEMORY_SCOPE_AGENT);
      if (hs_out)
        *(unsigned int*)(hs_out + ((size_t)t * NB + eb) * HID + k) = pk;
    }

    if (t + 1 < nsteps) {
      __syncthreads();   // vmcnt(0) drain: this block's hbx stores visible at L3
      if (tid == 0)
        __hip_atomic_fetch_add(&bar[(t * 8 + (blk & 7)) * 16], 1,
                               __ATOMIC_RELAXED, __HIP_MEMORY_SCOPE_AGENT);
      if (tid < 64) {
        const int* cp = &bar[(t * 8 + (lane & 7)) * 16];
        while (__hip_atomic_load(cp, __ATOMIC_RELAXED, __HIP_MEMORY_SCOPE_AGENT) < 8)
          __builtin_amdgcn_s_sleep(1);
      }
      __syncthreads();   // all h(t) visible; step t+1 loads ordered after poll
    }
  }

  if (hfin && tid < 256) {
    f32x2 hv; hv[0] = h32[eb][eil]; hv[1] = h32[eb][eil + 1];
    *(f32x2*)(hfin + (size_t)eb * HID + i0 + eil) = hv;
  }
}

// ---------------- log_softmax: bf16 logits (head of each row slot) -> fp32 d_out ----------------
// One block per row; bf16 row (64000 B) staged+converted into 125 KB LDS;
// single global read + single fp32 write (same block, ordered by syncthreads).
__global__ __launch_bounds__(1024, 1) void log_softmax_bf16(float* __restrict__ out) {
  __shared__ float rowbuf[VOCAB];            // 128000 B
  __shared__ float ms[16], ss[16];
  size_t row = blockIdx.x;
  const unsigned short* src = (const unsigned short*)out + row * (VOCAB * 2);
  int tid = threadIdx.x;
  float m = -3.0e38f, s = 0.f;
  for (int j = tid; j < VOCAB / 8; j += 1024) {
    u16x8 v = *(const u16x8*)(src + j * 8);
#pragma unroll
    for (int e = 0; e < 8; ++e) {
      float x = bf2f(v[e]);
      rowbuf[j * 8 + e] = x;
      float nm = fmaxf(m, x);
      s = s * __expf(m - nm) + __expf(x - nm);
      m = nm;
    }
  }
#pragma unroll
  for (int off = 1; off < 64; off <<= 1) {
    float m2 = __shfl_xor(m, off, 64);
    float s2 = __shfl_xor(s, off, 64);
    float nm = fmaxf(m, m2);
    s = s * __expf(m - nm) + s2 * __expf(m2 - nm);
    m = nm;
  }
  if ((tid & 63) == 0) { ms[tid >> 6] = m; ss[tid >> 6] = s; }
  __syncthreads();
  float M = -3.0e38f;
#pragma unroll
  for (int i = 0; i < 16; ++i) M = fmaxf(M, ms[i]);
  float S = 0.f;
#pragma unroll
  for (int i = 0; i < 16; ++i) S += ss[i] * __expf(ms[i] - M);
  float lse = M + __logf(S);
  f32x4* o4 = (f32x4*)(out + row * VOCAB);
  for (int j = tid; j < VOCAB / 4; j += 1024) {
    f32x4 v = *(const f32x4*)(rowbuf + j * 4);
    v[0] -= lse; v[1] -= lse; v[2] -= lse; v[3] -= lse;
    o4[j] = v;
  }
}

// ---------------- host ----------------

extern "C" void kernel_launch(void* const* d_in, const int* in_sizes, int n_in,
                              void* d_out, int out_size, void* d_ws, size_t ws_size,
                              hipStream_t stream) {
  (void)in_sizes; (void)n_in; (void)out_size; (void)ws_size;
  const int*   input_seqs  = (const int*)d_in[0];
  const int*   target_seqs = (const int*)d_in[1];
  const int*   input_lens  = (const int*)d_in[2];
  const float* emb_enc = (const float*)d_in[3];
  const float* W_ih_e  = (const float*)d_in[4];
  const float* W_hh_e  = (const float*)d_in[5];
  const float* b_ih_e  = (const float*)d_in[6];
  const float* b_hh_e  = (const float*)d_in[7];
  const float* emb_dec = (const float*)d_in[8];
  const float* W_ih_d  = (const float*)d_in[9];
  const float* W_hh_d  = (const float*)d_in[10];
  const float* b_ih_d  = (const float*)d_in[11];
  const float* b_hh_d  = (const float*)d_in[12];
  const float* W_out   = (const float*)d_in[13];
  const float* b_out   = (const float*)d_in[14];
  float* out = (float*)d_out;

  char* p = (char*)d_ws;
  auto take = [&](size_t n) { char* q = p; p += (n + 255) & ~(size_t)255; return q; };
  unsigned short* Wbf_e  = (unsigned short*)take((size_t)G3 * HID * 2);
  unsigned short* Wbf_1d = (unsigned short*)take((size_t)G3 * HID * 2);
  unsigned short* Wbf_2d = (unsigned short*)take((size_t)G3 * HID * 2);
  unsigned short* Wbf_o  = (unsigned short*)take((size_t)VOCAB * HID * 2);
  unsigned short* Wv_e   = (unsigned short*)take((size_t)G3 * HID * 2);
  unsigned short* Wv_d   = (unsigned short*)take((size_t)G3 * HID * 2);
  unsigned short* A_ed   = (unsigned short*)take((size_t)2048 * HID * 2);
  unsigned short* A_th   = (unsigned short*)take((size_t)128 * HID * 2);
  unsigned short* A_hs   = (unsigned short*)take((size_t)2048 * HID * 2);
  float* xpT = (float*)take((size_t)64 * 3 * NB * HID * 4);
  float* t2  = (float*)take((size_t)128 * G3 * 4);
  unsigned short* hbx_e = (unsigned short*)take((size_t)SLEN * NB * HID * 2);
  unsigned short* hbx_d = (unsigned short*)take((size_t)TLEN * NB * HID * 2);
  int*   bar_e = (int*)take((size_t)SLEN * 8 * 16 * 4);   // 8 sub-counters/step, 64B apart
  int*   bar_d = (int*)take((size_t)TLEN * 8 * 16 * 4);
  float* hfin = (float*)take((size_t)NB * HID * 4);

  // weight converts (fp32 -> bf16)
  cvt_bf16<<<dim3((G3 * HID) / 1024), 256, 0, stream>>>(W_ih_e, Wbf_e);
  cvt_split_d<<<dim3(G3), 256, 0, stream>>>(W_ih_d, Wbf_1d, Wbf_2d);
  cvt_bf16<<<dim3((VOCAB * HID) / 1024), 256, 0, stream>>>(W_out, Wbf_o);
  cvt_whh_frag<<<dim3(G3), 128, 0, stream>>>(W_hh_e, Wv_e);
  cvt_whh_frag<<<dim3(G3), 128, 0, stream>>>(W_hh_d, Wv_d);
  zero_f32<<<dim3(64), 256, 0, stream>>>((float*)bar_e);   // bar_e + bar_d (64 KB)

  // ---- encoder ----
  gather_embed<<<dim3(NB * SLEN), 256, 0, stream>>>(input_seqs, emb_enc, A_ed, 0);
  gemm_bf16<1, 16><<<dim3(384), 256, 0, stream>>>(A_ed, Wbf_e, b_ih_e, nullptr, xpT, G3);
  gru_scan<<<dim3(64), 384, 0, stream>>>(Wv_e, b_hh_e, xpT, hbx_e, input_lens,
                                         nullptr, hfin, bar_e, SLEN);

  // ---- decoder pre ----
  gather_thought<<<dim3(128), 256, 0, stream>>>(hfin, A_th);
  gemm_bf16<0, 1><<<dim3(24), 256, 0, stream>>>(A_th, Wbf_2d, b_ih_d, nullptr, t2, G3);
  gather_embed<<<dim3(NB * TLEN), 256, 0, stream>>>(target_seqs, emb_dec, A_ed, 1);
  gemm_bf16<2, 16><<<dim3(384), 256, 0, stream>>>(A_ed, Wbf_1d, nullptr, t2, xpT, G3);

  // ---- decoder scan ----
  gru_scan<<<dim3(64), 384, 0, stream>>>(Wv_d, b_hh_d, xpT, hbx_d, nullptr,
                                         A_hs, nullptr, bar_d, TLEN);

  // ---- logits (bf16, packed into d_out row slots) + log_softmax -> fp32 ----
  gemm_bf16<3, 16><<<dim3(4000), 256, 0, stream>>>(A_hs, Wbf_o, b_out, nullptr, out, VOCAB);
  log_softmax_bf16<<<dim3(NB * TLEN), 1024, 0, stream>>>(out);
}

// Round 11
// 815.065 us; speedup vs baseline: 1.3380x; 1.0679x over previous
//
#include <hip/hip_runtime.h>
#include <stdint.h>
#include <stddef.h>

#define VOCAB 32000
#define HID   1024
#define NB    32
#define SLEN  64
#define TLEN  64
#define G3    3072

typedef float          f32x4  __attribute__((ext_vector_type(4)));
typedef float          f32x2  __attribute__((ext_vector_type(2)));
typedef __bf16         bf16x8 __attribute__((ext_vector_type(8)));
typedef unsigned short u16x8  __attribute__((ext_vector_type(8)));
typedef unsigned short u16x4  __attribute__((ext_vector_type(4)));
typedef unsigned int   u32x4  __attribute__((ext_vector_type(4)));

union BfPun { u16x8 u; bf16x8 b; };
union CvPun { u32x4 u; bf16x8 b; };

__device__ __forceinline__ unsigned short f2bf(float f) {
  unsigned int u = __builtin_bit_cast(unsigned int, f);
  u += 0x7FFFu + ((u >> 16) & 1u);   // RNE round to bf16
  return (unsigned short)(u >> 16);
}
__device__ __forceinline__ float bf2f(unsigned short h) {
  unsigned int u = (unsigned int)h << 16;
  return __builtin_bit_cast(float, u);
}

// fast sigmoid / tanh via v_exp + v_rcp
__device__ __forceinline__ float sig_f(float x) {
  return __builtin_amdgcn_rcpf(1.f + __expf(-x));
}
__device__ __forceinline__ float tanh_f(float x) {
  return 2.f * __builtin_amdgcn_rcpf(1.f + __expf(-2.f * x)) - 1.f;
}

// async global -> LDS, 16 B per lane (LDS dest must be wave-uniform base + lane*16)
__device__ __forceinline__ void gld_lds16(const unsigned short* g, unsigned short* l) {
  __builtin_amdgcn_global_load_lds(
      (const __attribute__((address_space(1))) unsigned int*)g,
      (__attribute__((address_space(3))) unsigned int*)l,
      16, 0, 0);
}

// ---------------- converts / gathers / init ----------------

__global__ __launch_bounds__(256) void cvt_bf16(const float* __restrict__ in,
                                                unsigned short* __restrict__ out) {
  size_t idx = ((size_t)blockIdx.x * 256 + threadIdx.x) * 4;
  f32x4 v = *(const f32x4*)(in + idx);
  u16x4 o;
  o[0] = f2bf(v[0]); o[1] = f2bf(v[1]); o[2] = f2bf(v[2]); o[3] = f2bf(v[3]);
  *(u16x4*)(out + idx) = o;
}

// W_ih_d [3072][2048] -> W1 (cols 0..1023), W2 (cols 1024..2047), both bf16 [3072][1024]
__global__ __launch_bounds__(256) void cvt_split_d(const float* __restrict__ Wd,
                                                   unsigned short* __restrict__ W1,
                                                   unsigned short* __restrict__ W2) {
  int r = blockIdx.x, q = threadIdx.x;
  const float* src = Wd + (size_t)r * 2048;
  f32x4 v1 = *(const f32x4*)(src + q * 4);
  f32x4 v2 = *(const f32x4*)(src + 1024 + q * 4);
  u16x4 o1, o2;
  o1[0]=f2bf(v1[0]); o1[1]=f2bf(v1[1]); o1[2]=f2bf(v1[2]); o1[3]=f2bf(v1[3]);
  o2[0]=f2bf(v2[0]); o2[1]=f2bf(v2[1]); o2[2]=f2bf(v2[2]); o2[3]=f2bf(v2[3]);
  *(u16x4*)(W1 + (size_t)r * 1024 + q * 4) = o1;
  *(u16x4*)(W2 + (size_t)r * 1024 + q * 4) = o2;
}

// W_hh [3H][H] fp32 -> fragment-linear bf16: Wv[blk][g][ks][lane][8]
__global__ __launch_bounds__(128) void cvt_whh_frag(const float* __restrict__ W,
                                                    unsigned short* __restrict__ Wv) {
  int r = blockIdx.x;              // 0..3071
  int g = r >> 10, i = r & 1023, blk = i >> 4, il = i & 15;
  int q = threadIdx.x;             // 8-elem chunk 0..127
  int ks = q >> 2, ksub = q & 3, lane = il + ksub * 16;
  f32x4 v0 = *(const f32x4*)(W + (size_t)r * HID + q * 8);
  f32x4 v1 = *(const f32x4*)(W + (size_t)r * HID + q * 8 + 4);
  u16x8 o;
  o[0]=f2bf(v0[0]); o[1]=f2bf(v0[1]); o[2]=f2bf(v0[2]); o[3]=f2bf(v0[3]);
  o[4]=f2bf(v1[0]); o[5]=f2bf(v1[1]); o[6]=f2bf(v1[2]); o[7]=f2bf(v1[3]);
  size_t dst = ((((size_t)blk * 3 + g) * 32 + ks) * 64 + lane) * 8;
  *(u16x8*)(Wv + dst) = o;
}

__global__ __launch_bounds__(256) void gather_embed(const int* __restrict__ seqs,
                                                    const float* __restrict__ emb,
                                                    unsigned short* __restrict__ Aout,
                                                    int relu) {
  int r = blockIdx.x, q = threadIdx.x;
  int tok = seqs[r];
  f32x4 v = *(const f32x4*)(emb + (size_t)tok * HID + q * 4);
  if (relu) {
    v[0]=fmaxf(v[0],0.f); v[1]=fmaxf(v[1],0.f); v[2]=fmaxf(v[2],0.f); v[3]=fmaxf(v[3],0.f);
  }
  u16x4 o; o[0]=f2bf(v[0]); o[1]=f2bf(v[1]); o[2]=f2bf(v[2]); o[3]=f2bf(v[3]);
  *(u16x4*)(Aout + (size_t)r * HID + q * 4) = o;
}

// relu(thought) -> bf16, rows 32..127 zero-padded
__global__ __launch_bounds__(256) void gather_thought(const float* __restrict__ hfin,
                                                      unsigned short* __restrict__ Aout) {
  int r = blockIdx.x, q = threadIdx.x;
  u16x4 o = {0, 0, 0, 0};
  if (r < NB) {
    f32x4 v = *(const f32x4*)(hfin + (size_t)r * HID + q * 4);
    o[0]=f2bf(fmaxf(v[0],0.f)); o[1]=f2bf(fmaxf(v[1],0.f));
    o[2]=f2bf(fmaxf(v[2],0.f)); o[3]=f2bf(fmaxf(v[3],0.f));
  }
  *(u16x4*)(Aout + (size_t)r * HID + q * 4) = o;
}

__global__ __launch_bounds__(256) void zero_f32(float* __restrict__ p) {
  p[blockIdx.x * 256 + threadIdx.x] = 0.f;
}

// ---------------- 128-tile bf16 MFMA GEMM (xp projections) ----------------
// BK=64, gload_lds staging, involution chunk-swizzle (R9, bank-conflict-free).
template<int MODE, int MT>
__global__ __launch_bounds__(256) void gemm_bf16(const unsigned short* __restrict__ A,
                                                 const unsigned short* __restrict__ Bw,
                                                 const float* __restrict__ bias,
                                                 const float* __restrict__ add2,
                                                 void* __restrict__ outv, int N) {
  __shared__ unsigned short Abuf[128 * 64];
  __shared__ unsigned short Bbuf[128 * 64];
  const int K = HID;
  int tid = threadIdx.x, lane = tid & 63, wid = tid >> 6;
  int nwg = gridDim.x;
  int u = (blockIdx.x & 7) * (nwg >> 3) + (blockIdx.x >> 3);
  int g = u / (MT * 4);
  int r_ = u - g * (MT * 4);
  int bm = r_ % MT;
  int bn = g * 4 + r_ / MT;
  int wrow = wid >> 1, wcol = wid & 1;
  f32x4 zero4 = {0.f, 0.f, 0.f, 0.f};
  f32x4 acc[4][4];
#pragma unroll
  for (int i = 0; i < 4; ++i)
#pragma unroll
    for (int j = 0; j < 4; ++j) acc[i][j] = zero4;

  int srow = tid >> 3;                       // 0..31
  int csrc = (tid & 7) ^ (srow & 7);         // involution, constant per thread
  const unsigned short* Ag = A + ((size_t)bm * 128 + srow) * K + csrc * 8;
  const unsigned short* Bg = Bw + ((size_t)bn * 128 + srow) * K + csrc * 8;
  unsigned short* As = Abuf + tid * 8;
  unsigned short* Bs = Bbuf + tid * 8;

  int ca0 = (0 * 4 + (lane >> 4)) ^ (lane & 7);
  int ca1 = (1 * 4 + (lane >> 4)) ^ (lane & 7);

  for (int ks = 0; ks < 16; ++ks) {
    size_t k0 = ks * 64;
    __syncthreads();
#pragma unroll
    for (int j = 0; j < 4; ++j)
      gld_lds16(Ag + (size_t)j * 32 * K + k0, As + j * 2048);
#pragma unroll
    for (int j = 0; j < 4; ++j)
      gld_lds16(Bg + (size_t)j * 32 * K + k0, Bs + j * 2048);
    __syncthreads();
#pragma unroll
    for (int kk = 0; kk < 2; ++kk) {
      int cc = kk ? ca1 : ca0;
      bf16x8 af[4], bfr[4];
#pragma unroll
      for (int mi = 0; mi < 4; ++mi) {
        BfPun tpun;
        tpun.u = *(const u16x8*)(Abuf + (wrow * 64 + mi * 16 + (lane & 15)) * 64 + cc * 8);
        af[mi] = tpun.b;
      }
#pragma unroll
      for (int ni = 0; ni < 4; ++ni) {
        BfPun tpun;
        tpun.u = *(const u16x8*)(Bbuf + (wcol * 64 + ni * 16 + (lane & 15)) * 64 + cc * 8);
        bfr[ni] = tpun.b;
      }
#pragma unroll
      for (int mi = 0; mi < 4; ++mi)
#pragma unroll
        for (int ni = 0; ni < 4; ++ni)
          acc[mi][ni] = __builtin_amdgcn_mfma_f32_16x16x32_bf16(af[mi], bfr[ni], acc[mi][ni], 0, 0, 0);
    }
  }

  float* out = (float*)outv;
#pragma unroll
  for (int mi = 0; mi < 4; ++mi) {
    int rb = bm * 128 + wrow * 64 + mi * 16 + ((lane >> 4) << 2);
#pragma unroll
    for (int ni = 0; ni < 4; ++ni) {
      int c = bn * 128 + wcol * 64 + ni * 16 + (lane & 15);
#pragma unroll
      for (int e = 0; e < 4; ++e) {
        int r = rb + e;
        float v = acc[mi][ni][e];
        if (MODE == 0) {
          out[(size_t)r * N + c] = v + bias[c];
        } else if (MODE == 1) {
          int t = r & 63, b = r >> 6;
          int gg = c >> 10, ci = c & 1023;
          out[(((size_t)t * 3 + gg) * NB + b) * HID + ci] = v + bias[c];
        } else {
          int t = r & 63, b = r >> 6;
          int gg = c >> 10, ci = c & 1023;
          out[(((size_t)t * 3 + gg) * NB + b) * HID + ci] = v + add2[(size_t)b * G3 + c];
        }
      }
    }
  }
}

// ---------------- 256x256 8-phase logits GEMM (m201 template, T2+T3+T4+T5) ----------------
// 512 thr = 8 waves (2M x 4N); BK=64; LDS 128KB dbuf; raw s_barrier, counted vmcnt;
// bf16 output packed into the head of each d_out row slot.
__global__ __launch_bounds__(512, 1) void gemm_logits(const unsigned short* __restrict__ A,
                                                      const unsigned short* __restrict__ Bw,
                                                      const float* __restrict__ bias,
                                                      unsigned short* __restrict__ o16) {
  __shared__ unsigned short Al[2][16384];   // [buf][256 rows][64 k] bf16, 32 KB each
  __shared__ unsigned short Bl[2][16384];
  const int K = HID;
  int tid = threadIdx.x, lane = tid & 63, wid = tid >> 6;
  int wm = wid >> 2, wn = wid & 3;
  int u = (blockIdx.x & 7) * 125 + (blockIdx.x >> 3);  // XCD-chunked (1000 % 8 == 0)
  int bm = u & 7, bn = u >> 3;

  f32x4 acc[8][4];
  f32x4 zero4 = {0.f, 0.f, 0.f, 0.f};
#pragma unroll
  for (int a = 0; a < 8; ++a)
#pragma unroll
    for (int ni = 0; ni < 4; ++ni) acc[a][ni] = zero4;

  int srow = tid >> 3;                        // 0..63
  int csrc = (tid & 7) ^ (srow & 7);          // involution chunk swizzle
  const unsigned short* Ag = A + ((size_t)bm * 256 + srow) * K + csrc * 8;
  const unsigned short* Bg = Bw + ((size_t)bn * 256 + srow) * K + csrc * 8;

  int arow = wm * 128 + (lane & 15);          // + mh*64 + mi*16
  int bcol = wn * 64 + (lane & 15);           // + ni*16
  int ch0 = (lane >> 4) ^ (lane & 7);         // k-slice 0 chunk (swizzled)
  int ch1 = ((lane >> 4) + 4) ^ (lane & 7);   // k-slice 1 chunk

  // prologue: stage tile 0 -> buf 0
#pragma unroll
  for (int j = 0; j < 4; ++j) gld_lds16(Ag + (size_t)j * 64 * K, &Al[0][j * 4096 + tid * 8]);
#pragma unroll
  for (int j = 0; j < 4; ++j) gld_lds16(Bg + (size_t)j * 64 * K, &Bl[0][j * 4096 + tid * 8]);
  asm volatile("s_waitcnt vmcnt(0)" ::: "memory");
  __builtin_amdgcn_s_barrier();

  bf16x8 afr[4][2], bf0[2][2], bf1[2][2];

  for (int it = 0; it < 16; ++it) {
    int cur = it & 1, nxt = cur ^ 1;
    bool stage = (it < 15);
    size_t kof = (size_t)(it + 1) * 64;
    const unsigned short* Ac = &Al[cur][0];
    const unsigned short* Bc = &Bl[cur][0];

    // ---- P1: read A(mh0) + B(np0) ; stage A(t+1) ----
#pragma unroll
    for (int mi = 0; mi < 4; ++mi) {
      BfPun t0, t1;
      t0.u = *(const u16x8*)(Ac + (arow + mi * 16) * 64 + ch0 * 8);
      t1.u = *(const u16x8*)(Ac + (arow + mi * 16) * 64 + ch1 * 8);
      afr[mi][0] = t0.b; afr[mi][1] = t1.b;
    }
#pragma unroll
    for (int ni = 0; ni < 2; ++ni) {
      BfPun t0, t1;
      t0.u = *(const u16x8*)(Bc + (bcol + ni * 16) * 64 + ch0 * 8);
      t1.u = *(const u16x8*)(Bc + (bcol + ni * 16) * 64 + ch1 * 8);
      bf0[ni][0] = t0.b; bf0[ni][1] = t1.b;
    }
    if (stage) {
#pragma unroll
      for (int j = 0; j < 4; ++j)
        gld_lds16(Ag + kof + (size_t)j * 64 * K, &Al[nxt][j * 4096 + tid * 8]);
    }
    __builtin_amdgcn_s_barrier();
    __builtin_amdgcn_s_setprio(1);
#pragma unroll
    for (int mi = 0; mi < 4; ++mi)
#pragma unroll
      for (int ni = 0; ni < 2; ++ni)
#pragma unroll
        for (int ks = 0; ks < 2; ++ks)
          acc[mi][ni] = __builtin_amdgcn_mfma_f32_16x16x32_bf16(afr[mi][ks], bf0[ni][ks], acc[mi][ni], 0, 0, 0);
    __builtin_amdgcn_s_setprio(0);
    __builtin_amdgcn_s_barrier();

    // ---- P2: read B(np1) ; stage B(t+1) ----
#pragma unroll
    for (int ni = 0; ni < 2; ++ni) {
      BfPun t0, t1;
      t0.u = *(const u16x8*)(Bc + (bcol + (ni + 2) * 16) * 64 + ch0 * 8);
      t1.u = *(const u16x8*)(Bc + (bcol + (ni + 2) * 16) * 64 + ch1 * 8);
      bf1[ni][0] = t0.b; bf1[ni][1] = t1.b;
    }
    if (stage) {
#pragma unroll
      for (int j = 0; j < 4; ++j)
        gld_lds16(Bg + kof + (size_t)j * 64 * K, &Bl[nxt][j * 4096 + tid * 8]);
    }
    __builtin_amdgcn_s_barrier();
    __builtin_amdgcn_s_setprio(1);
#pragma unroll
    for (int mi = 0; mi < 4; ++mi)
#pragma unroll
      for (int ni = 0; ni < 2; ++ni)
#pragma unroll
        for (int ks = 0; ks < 2; ++ks)
          acc[mi][2 + ni] = __builtin_amdgcn_mfma_f32_16x16x32_bf16(afr[mi][ks], bf1[ni][ks], acc[mi][2 + ni], 0, 0, 0);
    __builtin_amdgcn_s_setprio(0);
    __builtin_amdgcn_s_barrier();

    // ---- P3: read A(mh1) ; MFMA (mh1, np0) with held bf0 ----
#pragma unroll
    for (int mi = 0; mi < 4; ++mi) {
      BfPun t0, t1;
      t0.u = *(const u16x8*)(Ac + (arow + 64 + mi * 16) * 64 + ch0 * 8);
      t1.u = *(const u16x8*)(Ac + (arow + 64 + mi * 16) * 64 + ch1 * 8);
      afr[mi][0] = t0.b; afr[mi][1] = t1.b;
    }
    __builtin_amdgcn_s_barrier();
    __builtin_amdgcn_s_setprio(1);
#pragma unroll
    for (int mi = 0; mi < 4; ++mi)
#pragma unroll
      for (int ni = 0; ni < 2; ++ni)
#pragma unroll
        for (int ks = 0; ks < 2; ++ks)
          acc[4 + mi][ni] = __builtin_amdgcn_mfma_f32_16x16x32_bf16(afr[mi][ks], bf0[ni][ks], acc[4 + mi][ni], 0, 0, 0);
    __builtin_amdgcn_s_setprio(0);
    __builtin_amdgcn_s_barrier();

    // ---- P4: MFMA (mh1, np1) ; counted vmcnt for tile t+1 before swap ----
    __builtin_amdgcn_s_setprio(1);
#pragma unroll
    for (int mi = 0; mi < 4; ++mi)
#pragma unroll
      for (int ni = 0; ni < 2; ++ni)
#pragma unroll
        for (int ks = 0; ks < 2; ++ks)
          acc[4 + mi][2 + ni] = __builtin_amdgcn_mfma_f32_16x16x32_bf16(afr[mi][ks], bf1[ni][ks], acc[4 + mi][2 + ni], 0, 0, 0);
    __builtin_amdgcn_s_setprio(0);
    if (stage) asm volatile("s_waitcnt vmcnt(0)" ::: "memory");
    __builtin_amdgcn_s_barrier();
  }

  // epilogue: bf16 logits into d_out row slots
#pragma unroll
  for (int a = 0; a < 8; ++a) {
    int r0 = bm * 256 + wm * 128 + (a >> 2) * 64 + (a & 3) * 16 + ((lane >> 4) << 2);
#pragma unroll
    for (int ni = 0; ni < 4; ++ni) {
      int c = bn * 256 + wn * 64 + ni * 16 + (lane & 15);
      float bs = bias[c];
#pragma unroll
      for (int e = 0; e < 4; ++e) {
        int r = r0 + e;
        int b = r & 31, t = r >> 5;
        o16[(size_t)(b * 64 + t) * (VOCAB * 2) + c] = f2bf(acc[a][ni][e] + bs);
      }
    }
  }
}

// ---------------- persistent GRU scan (unchanged from R9) ----------------
__global__ __launch_bounds__(384, 1) void gru_scan(
    const unsigned short* __restrict__ Wv,
    const float* __restrict__ b_hh,
    const float* __restrict__ xpT,
    unsigned short* __restrict__ hbx,
    const int* __restrict__ lens,
    unsigned short* __restrict__ hs_out,
    float* __restrict__ hfin,
    int* __restrict__ bar, int nsteps) {
  __shared__ unsigned short Wlds[49152];
  __shared__ float gh[48][33];
  __shared__ float h32[32][16];
  __shared__ float bhh_s[48];
  __shared__ int   lens_s[32];
  int tid = threadIdx.x, lane = tid & 63, w = tid >> 6;
  int g = w >> 1, part = w & 1;
  int blk = blockIdx.x, i0 = blk * 16;

  if (tid < 32) lens_s[tid] = lens ? lens[tid] : 0x7fffffff;
  if (tid >= 64 && tid < 112) {
    int q = tid - 64;
    bhh_s[q] = b_hh[(size_t)(q >> 4) * HID + i0 + (q & 15)];
  }
  if (tid < 256) h32[tid >> 3][((tid & 7) * 2)] = 0.f;
  if (tid < 256) h32[tid >> 3][((tid & 7) * 2) + 1] = 0.f;

  {
    const unsigned short* Wsrc = Wv + (size_t)blk * 49152;
    for (int j = tid; j < 6144; j += 384)
      *(u16x8*)(Wlds + (size_t)j * 8) = *(const u16x8*)(Wsrc + (size_t)j * 8);
  }
  __syncthreads();

  int eb = tid >> 3, eil = (tid & 7) * 2;
  f32x2 xr2, xz2, xn2;

  for (int t = 0; t < nsteps; ++t) {
    if (tid < 256) {
      const float* xb = xpT + ((size_t)t * 3 * NB + eb) * HID + i0 + eil;
      xr2 = *(const f32x2*)(xb);
      xz2 = *(const f32x2*)(xb + (size_t)NB * HID);
      xn2 = *(const f32x2*)(xb + (size_t)2 * NB * HID);
    }
    f32x4 acc = {0.f, 0.f, 0.f, 0.f};
    if (t > 0) {
      const unsigned short* hp = hbx + (size_t)(t - 1) * 32768 + part * 16384 + lane * 8;
      u32x4 pb[16];
#pragma unroll
      for (int j = 0; j < 16; ++j) pb[j] = *(const u32x4*)(hp + (size_t)j * 512);
#pragma unroll
      for (int ks = 0; ks < 32; ++ks) {
        BfPun a_;
        a_.u = *(const u16x8*)(Wlds + ((size_t)(g * 32 + ks) * 64 + lane) * 8);
        CvPun cv; cv.u = pb[ks & 15];
        if (ks + 16 < 32) pb[ks & 15] = *(const u32x4*)(hp + (size_t)(ks + 16) * 512);
        acc = __builtin_amdgcn_mfma_f32_16x16x32_bf16(a_.b, cv.b, acc, 0, 0, 0);
      }
    }
    {
      int il4 = (lane >> 4) * 4, cb = part * 16 + (lane & 15);
#pragma unroll
      for (int e = 0; e < 4; ++e) gh[g * 16 + il4 + e][cb] = acc[e];
    }
    __syncthreads();

    if (tid < 256) {
      float sr0 = gh[eil][eb],      sr1 = gh[eil + 1][eb];
      float sz0 = gh[16 + eil][eb], sz1 = gh[16 + eil + 1][eb];
      float sn0 = gh[32 + eil][eb], sn1 = gh[32 + eil + 1][eb];
      float rg0 = sig_f(xr2[0] + sr0 + bhh_s[eil]);
      float rg1 = sig_f(xr2[1] + sr1 + bhh_s[eil + 1]);
      float zg0 = sig_f(xz2[0] + sz0 + bhh_s[16 + eil]);
      float zg1 = sig_f(xz2[1] + sz1 + bhh_s[16 + eil + 1]);
      float ng0 = tanh_f(xn2[0] + rg0 * (sn0 + bhh_s[32 + eil]));
      float ng1 = tanh_f(xn2[1] + rg1 * (sn1 + bhh_s[32 + eil + 1]));
      float h0o = h32[eb][eil], h1o = h32[eb][eil + 1];
      float hn0 = (1.f - zg0) * ng0 + zg0 * h0o;
      float hn1 = (1.f - zg1) * ng1 + zg1 * h1o;
      if (t >= lens_s[eb]) { hn0 = h0o; hn1 = h1o; }
      h32[eb][eil] = hn0; h32[eb][eil + 1] = hn1;
      unsigned int pk = (unsigned int)f2bf(hn0) | ((unsigned int)f2bf(hn1) << 16);
      int k = i0 + eil;
      int ksf = k >> 5, lnf = (eb & 15) + ((k >> 3) & 3) * 16, sub = k & 7;
      unsigned short* dst = hbx + (size_t)t * 32768 + (size_t)(eb >> 4) * 16384
                            + (size_t)ksf * 512 + lnf * 8 + sub;
      __hip_atomic_store((unsigned int*)dst, pk, __ATOMIC_RELAXED, __HIP_MEMORY_SCOPE_AGENT);
      if (hs_out)
        *(unsigned int*)(hs_out + ((size_t)t * NB + eb) * HID + k) = pk;
    }

    if (t + 1 < nsteps) {
      __syncthreads();
      if (tid == 0)
        __hip_atomic_fetch_add(&bar[(t * 8 + (blk & 7)) * 16], 1,
                               __ATOMIC_RELAXED, __HIP_MEMORY_SCOPE_AGENT);
      if (tid < 64) {
        const int* cp = &bar[(t * 8 + (lane & 7)) * 16];
        while (__hip_atomic_load(cp, __ATOMIC_RELAXED, __HIP_MEMORY_SCOPE_AGENT) < 8)
          __builtin_amdgcn_s_sleep(1);
      }
      __syncthreads();
    }
  }

  if (hfin && tid < 256) {
    f32x2 hv; hv[0] = h32[eb][eil]; hv[1] = h32[eb][eil + 1];
    *(f32x2*)(hfin + (size_t)eb * HID + i0 + eil) = hv;
  }
}

// ---------------- log_softmax: bf16 logits -> fp32 d_out (unchanged) ----------------
__global__ __launch_bounds__(1024, 1) void log_softmax_bf16(float* __restrict__ out) {
  __shared__ float rowbuf[VOCAB];
  __shared__ float ms[16], ss[16];
  size_t row = blockIdx.x;
  const unsigned short* src = (const unsigned short*)out + row * (VOCAB * 2);
  int tid = threadIdx.x;
  float m = -3.0e38f, s = 0.f;
  for (int j = tid; j < VOCAB / 8; j += 1024) {
    u16x8 v = *(const u16x8*)(src + j * 8);
#pragma unroll
    for (int e = 0; e < 8; ++e) {
      float x = bf2f(v[e]);
      rowbuf[j * 8 + e] = x;
      float nm = fmaxf(m, x);
      s = s * __expf(m - nm) + __expf(x - nm);
      m = nm;
    }
  }
#pragma unroll
  for (int off = 1; off < 64; off <<= 1) {
    float m2 = __shfl_xor(m, off, 64);
    float s2 = __shfl_xor(s, off, 64);
    float nm = fmaxf(m, m2);
    s = s * __expf(m - nm) + s2 * __expf(m2 - nm);
    m = nm;
  }
  if ((tid & 63) == 0) { ms[tid >> 6] = m; ss[tid >> 6] = s; }
  __syncthreads();
  float M = -3.0e38f;
#pragma unroll
  for (int i = 0; i < 16; ++i) M = fmaxf(M, ms[i]);
  float S = 0.f;
#pragma unroll
  for (int i = 0; i < 16; ++i) S += ss[i] * __expf(ms[i] - M);
  float lse = M + __logf(S);
  f32x4* o4 = (f32x4*)(out + row * VOCAB);
  for (int j = tid; j < VOCAB / 4; j += 1024) {
    f32x4 v = *(const f32x4*)(rowbuf + j * 4);
    v[0] -= lse; v[1] -= lse; v[2] -= lse; v[3] -= lse;
    o4[j] = v;
  }
}

// ---------------- host ----------------

extern "C" void kernel_launch(void* const* d_in, const int* in_sizes, int n_in,
                              void* d_out, int out_size, void* d_ws, size_t ws_size,
                              hipStream_t stream) {
  (void)in_sizes; (void)n_in; (void)out_size; (void)ws_size;
  const int*   input_seqs  = (const int*)d_in[0];
  const int*   target_seqs = (const int*)d_in[1];
  const int*   input_lens  = (const int*)d_in[2];
  const float* emb_enc = (const float*)d_in[3];
  const float* W_ih_e  = (const float*)d_in[4];
  const float* W_hh_e  = (const float*)d_in[5];
  const float* b_ih_e  = (const float*)d_in[6];
  const float* b_hh_e  = (const float*)d_in[7];
  const float* emb_dec = (const float*)d_in[8];
  const float* W_ih_d  = (const float*)d_in[9];
  const float* W_hh_d  = (const float*)d_in[10];
  const float* b_ih_d  = (const float*)d_in[11];
  const float* b_hh_d  = (const float*)d_in[12];
  const float* W_out   = (const float*)d_in[13];
  const float* b_out   = (const float*)d_in[14];
  float* out = (float*)d_out;

  char* p = (char*)d_ws;
  auto take = [&](size_t n) { char* q = p; p += (n + 255) & ~(size_t)255; return q; };
  unsigned short* Wbf_e  = (unsigned short*)take((size_t)G3 * HID * 2);
  unsigned short* Wbf_1d = (unsigned short*)take((size_t)G3 * HID * 2);
  unsigned short* Wbf_2d = (unsigned short*)take((size_t)G3 * HID * 2);
  unsigned short* Wbf_o  = (unsigned short*)take((size_t)VOCAB * HID * 2);
  unsigned short* Wv_e   = (unsigned short*)take((size_t)G3 * HID * 2);
  unsigned short* Wv_d   = (unsigned short*)take((size_t)G3 * HID * 2);
  unsigned short* A_ed   = (unsigned short*)take((size_t)2048 * HID * 2);
  unsigned short* A_th   = (unsigned short*)take((size_t)128 * HID * 2);
  unsigned short* A_hs   = (unsigned short*)take((size_t)2048 * HID * 2);
  float* xpT = (float*)take((size_t)64 * 3 * NB * HID * 4);
  float* t2  = (float*)take((size_t)128 * G3 * 4);
  unsigned short* hbx_e = (unsigned short*)take((size_t)SLEN * NB * HID * 2);
  unsigned short* hbx_d = (unsigned short*)take((size_t)TLEN * NB * HID * 2);
  int*   bar_e = (int*)take((size_t)SLEN * 8 * 16 * 4);
  int*   bar_d = (int*)take((size_t)TLEN * 8 * 16 * 4);
  float* hfin = (float*)take((size_t)NB * HID * 4);

  // weight converts (fp32 -> bf16)
  cvt_bf16<<<dim3((G3 * HID) / 1024), 256, 0, stream>>>(W_ih_e, Wbf_e);
  cvt_split_d<<<dim3(G3), 256, 0, stream>>>(W_ih_d, Wbf_1d, Wbf_2d);
  cvt_bf16<<<dim3((VOCAB * HID) / 1024), 256, 0, stream>>>(W_out, Wbf_o);
  cvt_whh_frag<<<dim3(G3), 128, 0, stream>>>(W_hh_e, Wv_e);
  cvt_whh_frag<<<dim3(G3), 128, 0, stream>>>(W_hh_d, Wv_d);
  zero_f32<<<dim3(64), 256, 0, stream>>>((float*)bar_e);

  // ---- encoder ----
  gather_embed<<<dim3(NB * SLEN), 256, 0, stream>>>(input_seqs, emb_enc, A_ed, 0);
  gemm_bf16<1, 16><<<dim3(384), 256, 0, stream>>>(A_ed, Wbf_e, b_ih_e, nullptr, xpT, G3);
  gru_scan<<<dim3(64), 384, 0, stream>>>(Wv_e, b_hh_e, xpT, hbx_e, input_lens,
                                         nullptr, hfin, bar_e, SLEN);

  // ---- decoder pre ----
  gather_thought<<<dim3(128), 256, 0, stream>>>(hfin, A_th);
  gemm_bf16<0, 1><<<dim3(24), 256, 0, stream>>>(A_th, Wbf_2d, b_ih_d, nullptr, t2, G3);
  gather_embed<<<dim3(NB * TLEN), 256, 0, stream>>>(target_seqs, emb_dec, A_ed, 1);
  gemm_bf16<2, 16><<<dim3(384), 256, 0, stream>>>(A_ed, Wbf_1d, nullptr, t2, xpT, G3);

  // ---- decoder scan ----
  gru_scan<<<dim3(64), 384, 0, stream>>>(Wv_d, b_hh_d, xpT, hbx_d, nullptr,
                                         A_hs, nullptr, bar_d, TLEN);

  // ---- logits (256^2 8-phase, bf16 into d_out row slots) + log_softmax ----
  gemm_logits<<<dim3(1000), 512, 0, stream>>>(A_hs, Wbf_o, b_out, (unsigned short*)out);
  log_softmax_bf16<<<dim3(NB * TLEN), 1024, 0, stream>>>(out);
}